// Round 6
// baseline (606.830 us; speedup 1.0000x reference)
//
#include <hip/hip_runtime.h>
#include <hip/hip_bf16.h>

typedef __attribute__((ext_vector_type(8))) short short8;
typedef __attribute__((ext_vector_type(4))) float f32x4;

constexpr int cB = 4, cN = 8192, cC = 512, cH = 8, cD = 64;
constexpr int cM = cB * cN;        // 32768 tokens
constexpr int cHD = cH * cD;       // 512
constexpr int cBH = cB * cH;       // 32
constexpr float kEPS = 1e-6f;
constexpr int KV_SPLIT = 32;       // k45 split-K slices

// ---- split f32 -> (bf16 hi by truncation, bf16 lo of remainder) ----
__device__ __forceinline__ void split2(float f, ushort& h, ushort& l) {
  unsigned u = __float_as_uint(f);
  h = (ushort)(u >> 16);
  float fl = f - __uint_as_float(u & 0xffff0000u);
  l = (ushort)(__float_as_uint(fl) >> 16);
}
__device__ __forceinline__ int pack_hi(float a, float b) {
  return (int)((__float_as_uint(a) >> 16) | (__float_as_uint(b) & 0xffff0000u));
}
__device__ __forceinline__ int pack_lo(float a, float b) {
  float la = a - __uint_as_float(__float_as_uint(a) & 0xffff0000u);
  float lb = b - __uint_as_float(__float_as_uint(b) & 0xffff0000u);
  return (int)((__float_as_uint(la) >> 16) | (__float_as_uint(lb) & 0xffff0000u));
}

// ---------------- splitter: f32 -> bf16 hi/lo (weights only) ----------------
__global__ __launch_bounds__(256) void split_w(const float* __restrict__ src,
    ushort* __restrict__ hi, ushort* __restrict__ lo, int n4) {
  int i = blockIdx.x * 256 + threadIdx.x;
  if (i >= n4) return;
  float4 v = reinterpret_cast<const float4*>(src)[i];
  ushort4 h, l;
  split2(v.x, h.x, l.x); split2(v.y, h.y, l.y);
  split2(v.z, h.z, l.z); split2(v.w, h.w, l.w);
  reinterpret_cast<ushort4*>(hi)[i] = h;
  reinterpret_cast<ushort4*>(lo)[i] = l;
}

// ---------------- split-bf16 MFMA GEMM: C = A[Mx512] @ W[NCx512]^T ----------------
// Double-buffered LDS, ONE barrier per K-step: issue next-tile stages at top,
// MFMA on current buffer, A convert+ds_write after MFMA, then __syncthreads.
// EPI=0 (NY=12): A f32 reg-staged, converted to bf16 hi/lo, swizzled ds_write.
//                Epilogue scatters qkv (sigmoid q,k; v*0.125) + fused qsum/ksum.
// EPI=1 (NY=4):  A pre-split bf16 hi/lo via global_load_lds. Epilogue: out+bias.
// All LDS tiles XOR-unit-swizzled (both-sides involution, rule #21).
// XCD-chunked bijective block swizzle (T1): nwg % 8 == 0 for both launches.
template<int EPI, int NY>
__global__ __launch_bounds__(256) void gemm_mfma(
    const float* __restrict__ A,
    const ushort* __restrict__ Ah_g, const ushort* __restrict__ Al_g,
    const ushort* __restrict__ Wh, const ushort* __restrict__ Wl,
    const float* __restrict__ bias,
    float* __restrict__ o0, float* __restrict__ o1, float* __restrict__ o2,
    float* __restrict__ qsum, float* __restrict__ ksum) {
  constexpr bool AF32 = (EPI == 0);
  constexpr int NT = cC / 32;                   // 16 K-steps of BK=32
  __shared__ ushort AhS[2][128 * 32], AlS[2][128 * 32];
  __shared__ ushort BhS[2][128 * 32], BlS[2][128 * 32];
  __shared__ float colsum[128];
  const int t = threadIdx.x;
  const int wave = t >> 6, lane = t & 63;
  const int wm = wave >> 1, wn = wave & 1;      // 2x2 waves of 64x64
  const int l15 = lane & 15, lg = lane >> 4;

  // ---- XCD-chunked bijective swizzle: y-fastest so same-row blocks co-reside ----
  const int raw = blockIdx.y * gridDim.x + blockIdx.x;
  const int q8 = (int)(gridDim.x * NY) >> 3;
  const int wg2 = (raw & 7) * q8 + (raw >> 3);
  const int rowchunk = wg2 / NY, ycol = wg2 - rowchunk * NY;
  const int row0 = rowchunk * 128, col0 = ycol * 128;

  if (EPI == 0 && t < 128) colsum[t] = 0.f;     // ordered by prologue barrier

  f32x4 acc[4][4] = {};

  const int srow = lane >> 2, sunit = lane & 3; // bf16 gld_lds stage mapping
  const int arow = t >> 1, akh = (t & 1) * 16;  // A f32 reg-stage mapping
  const float* aptr = AF32 ? (A + (size_t)(row0 + arow) * cC + akh) : nullptr;
  const int akey = (arow >> 1) & 3;
  const int au0 = (t & 1) * 2;

  float4 pa0, pa1, pa2, pa3;                    // A prefetch regs (EPI=0)

#define STAGE_B(buf, k0)                                                        \
  _Pragma("unroll")                                                             \
  for (int hh = 0; hh < 2; ++hh) {                                              \
    const int br = wave * 32 + hh * 16 + srow;                                  \
    const int sw = sunit ^ ((br >> 1) & 3);                                     \
    const size_t goff = (size_t)(col0 + br) * cC + (k0) + sw * 8;               \
    __builtin_amdgcn_global_load_lds(                                           \
        (const __attribute__((address_space(1))) void*)(Wh + goff),             \
        (__attribute__((address_space(3))) void*)(&BhS[buf][(wave * 32 + hh * 16) * 32]), \
        16, 0, 0);                                                              \
    __builtin_amdgcn_global_load_lds(                                           \
        (const __attribute__((address_space(1))) void*)(Wl + goff),             \
        (__attribute__((address_space(3))) void*)(&BlS[buf][(wave * 32 + hh * 16) * 32]), \
        16, 0, 0);                                                              \
  }

#define STAGE_A_PRE(buf, k0)                                                    \
  _Pragma("unroll")                                                             \
  for (int hh = 0; hh < 2; ++hh) {                                              \
    const int ar = wave * 32 + hh * 16 + srow;                                  \
    const int sw = sunit ^ ((ar >> 1) & 3);                                     \
    const size_t goff = (size_t)(row0 + ar) * cC + (k0) + sw * 8;               \
    __builtin_amdgcn_global_load_lds(                                           \
        (const __attribute__((address_space(1))) void*)(Ah_g + goff),           \
        (__attribute__((address_space(3))) void*)(&AhS[buf][(wave * 32 + hh * 16) * 32]), \
        16, 0, 0);                                                              \
    __builtin_amdgcn_global_load_lds(                                           \
        (const __attribute__((address_space(1))) void*)(Al_g + goff),           \
        (__attribute__((address_space(3))) void*)(&AlS[buf][(wave * 32 + hh * 16) * 32]), \
        16, 0, 0);                                                              \
  }

#define LOAD_A_REGS(k0)                                                         \
  pa0 = *(const float4*)(aptr + (k0) + 0);                                      \
  pa1 = *(const float4*)(aptr + (k0) + 4);                                      \
  pa2 = *(const float4*)(aptr + (k0) + 8);                                      \
  pa3 = *(const float4*)(aptr + (k0) + 12);

#define CONVERT_WRITE_A(buf)                                                    \
  {                                                                             \
    int4 H0 = make_int4(pack_hi(pa0.x, pa0.y), pack_hi(pa0.z, pa0.w),           \
                        pack_hi(pa1.x, pa1.y), pack_hi(pa1.z, pa1.w));          \
    int4 H1 = make_int4(pack_hi(pa2.x, pa2.y), pack_hi(pa2.z, pa2.w),           \
                        pack_hi(pa3.x, pa3.y), pack_hi(pa3.z, pa3.w));          \
    int4 L0 = make_int4(pack_lo(pa0.x, pa0.y), pack_lo(pa0.z, pa0.w),           \
                        pack_lo(pa1.x, pa1.y), pack_lo(pa1.z, pa1.w));          \
    int4 L1 = make_int4(pack_lo(pa2.x, pa2.y), pack_lo(pa2.z, pa2.w),           \
                        pack_lo(pa3.x, pa3.y), pack_lo(pa3.z, pa3.w));          \
    *(int4*)&AhS[buf][arow * 32 + ((au0 + 0) ^ akey) * 8] = H0;                 \
    *(int4*)&AhS[buf][arow * 32 + ((au0 + 1) ^ akey) * 8] = H1;                 \
    *(int4*)&AlS[buf][arow * 32 + ((au0 + 0) ^ akey) * 8] = L0;                 \
    *(int4*)&AlS[buf][arow * 32 + ((au0 + 1) ^ akey) * 8] = L1;                 \
  }

  // ---- prologue: fill buf 0 ----
  STAGE_B(0, 0);
  if (AF32) { LOAD_A_REGS(0); CONVERT_WRITE_A(0); }
  else      { STAGE_A_PRE(0, 0); }
  __syncthreads();

  int cur = 0;
  for (int kt = 0; kt < NT; ++kt) {
    // ---- issue next-tile stages into buf cur^1 ----
    if (kt + 1 < NT) {
      STAGE_B(cur ^ 1, (kt + 1) * 32);
      if (AF32) { LOAD_A_REGS((kt + 1) * 32); }
      else      { STAGE_A_PRE(cur ^ 1, (kt + 1) * 32); }
    }
    // ---- fragments from buf cur + 3-product MFMA ----
    short8 ah[4], al[4];
    #pragma unroll
    for (int mi = 0; mi < 4; ++mi) {
      const int r = wm * 64 + mi * 16 + l15;
      const int aidx = r * 32 + (lg ^ ((r >> 1) & 3)) * 8;
      ah[mi] = *reinterpret_cast<const short8*>(&AhS[cur][aidx]);
      al[mi] = *reinterpret_cast<const short8*>(&AlS[cur][aidx]);
    }
    #pragma unroll
    for (int ni = 0; ni < 4; ++ni) {
      const int c = wn * 64 + ni * 16 + l15;
      const int bidx = c * 32 + (lg ^ ((c >> 1) & 3)) * 8;
      const short8 bh = *reinterpret_cast<const short8*>(&BhS[cur][bidx]);
      const short8 bl = *reinterpret_cast<const short8*>(&BlS[cur][bidx]);
      #pragma unroll
      for (int mi = 0; mi < 4; ++mi) {
        acc[mi][ni] = __builtin_amdgcn_mfma_f32_16x16x32_bf16(ah[mi], bh, acc[mi][ni], 0, 0, 0);
        acc[mi][ni] = __builtin_amdgcn_mfma_f32_16x16x32_bf16(al[mi], bh, acc[mi][ni], 0, 0, 0);
        acc[mi][ni] = __builtin_amdgcn_mfma_f32_16x16x32_bf16(ah[mi], bl, acc[mi][ni], 0, 0, 0);
      }
    }
    // ---- A convert + swizzled ds_write into buf cur^1 (after MFMA: T14) ----
    if (AF32 && kt + 1 < NT) CONVERT_WRITE_A(cur ^ 1);
    __syncthreads();
    cur ^= 1;
  }
#undef STAGE_B
#undef STAGE_A_PRE
#undef LOAD_A_REGS
#undef CONVERT_WRITE_A

  // ---- epilogue: C/D map col=lane&15, row=(lane>>4)*4+r ----
  const bool qk_block = (EPI == 0) && (ycol < 8);
  float csum[4] = {};
  #pragma unroll
  for (int mi = 0; mi < 4; ++mi) {
    #pragma unroll
    for (int ni = 0; ni < 4; ++ni) {
      const int col = col0 + wn * 64 + ni * 16 + l15;
      #pragma unroll
      for (int r = 0; r < 4; ++r) {
        const int m = row0 + wm * 64 + mi * 16 + lg * 4 + r;
        const float val = acc[mi][ni][r];
        if (EPI == 0) {
          const int which = col >> 9;
          const int c2 = col & 511;
          const int h = c2 >> 6, d = c2 & 63;
          const int bb = m >> 13, n = m & 8191;
          const size_t idx = (((size_t)(bb * cH + h)) * cN + n) * cD + d;
          if (which < 2) {
            const float sv = 1.f / (1.f + __expf(-val));
            if (which == 0) o0[idx] = sv; else o1[idx] = sv;
            csum[ni] += sv;
          } else {
            o2[idx] = val * 0.125f;
          }
        } else {
          o0[(size_t)m * cC + col] = val + bias[col];
        }
      }
    }
  }
  if (qk_block) {
    #pragma unroll
    for (int ni = 0; ni < 4; ++ni)
      atomicAdd(&colsum[wn * 64 + ni * 16 + l15], csum[ni]);
    __syncthreads();
    if (t < 128) {
      const int col = col0 + t;
      const int c2 = col & 511;
      const int h = c2 >> 6, d = c2 & 63;
      const int bb = row0 >> 13;
      float* tgt = (col < 512) ? qsum : ksum;
      atomicAdd(&tgt[(bb * cH + h) * cD + d], colsum[t]);
    }
  }
}

// ---------------- K34: si, so; accumulate Sq, Sk (4 rows/wave/iter, float4) ----------------
__global__ __launch_bounds__(256) void k34_flow(const float* __restrict__ q,
      const float* __restrict__ k, const float* __restrict__ qsum,
      const float* __restrict__ ksum, float* __restrict__ si,
      float* __restrict__ Sq, float* __restrict__ Sk) {
  const int bh = blockIdx.x;
  const int n0 = blockIdx.y * 256;
  const int t = threadIdx.x;
  const int wave = t >> 6, lane = t & 63;
  const int g = lane >> 4, j = lane & 15;
  const float* qb = q + (size_t)bh * cN * cD;
  const float* kb = k + (size_t)bh * cN * cD;
  const float4 ks4 = *(const float4*)&ksum[bh * 64 + j * 4];
  const float4 qs4 = *(const float4*)&qsum[bh * 64 + j * 4];
  const float ksd[4] = {ks4.x + kEPS, ks4.y + kEPS, ks4.z + kEPS, ks4.w + kEPS};
  const float qsd[4] = {qs4.x + kEPS, qs4.y + kEPS, qs4.z + kEPS, qs4.w + kEPS};
  float aSq[4] = {}, aSk[4] = {};
  for (int i = 0; i < 16; ++i) {
    const int n = n0 + wave * 64 + i * 4 + g;
    const float4 q4 = *(const float4*)&qb[(size_t)n * cD + j * 4];
    const float4 k4 = *(const float4*)&kb[(size_t)n * cD + j * 4];
    const float qa[4] = {q4.x, q4.y, q4.z, q4.w};
    const float ka[4] = {k4.x, k4.y, k4.z, k4.w};
    float t1 = 0.f, t2 = 0.f;
    #pragma unroll
    for (int c = 0; c < 4; ++c) {
      t1 = fmaf(qa[c] + kEPS, ksd[c], t1);
      t2 = fmaf(ka[c] + kEPS, qsd[c], t2);
    }
    #pragma unroll
    for (int off = 1; off < 16; off <<= 1) {
      t1 += __shfl_xor(t1, off);
      t2 += __shfl_xor(t2, off);
    }
    const float si_n = 1.f / (t1 + kEPS);
    const float so_n = 1.f / (t2 + kEPS);
    if (j == 0) si[(size_t)bh * cN + n] = si_n;
    #pragma unroll
    for (int c = 0; c < 4; ++c) {
      aSq[c] = fmaf(qa[c], si_n, aSq[c]);
      aSk[c] = fmaf(ka[c], so_n, aSk[c]);
    }
  }
  #pragma unroll
  for (int c = 0; c < 4; ++c) {
    aSq[c] += __shfl_xor(aSq[c], 16); aSq[c] += __shfl_xor(aSq[c], 32);
    aSk[c] += __shfl_xor(aSk[c], 16); aSk[c] += __shfl_xor(aSk[c], 32);
  }
  __shared__ float sAq[4][64], sAk[4][64];
  if (g == 0) {
    #pragma unroll
    for (int c = 0; c < 4; ++c) { sAq[wave][j * 4 + c] = aSq[c]; sAk[wave][j * 4 + c] = aSk[c]; }
  }
  __syncthreads();
  if (t < 64) {
    atomicAdd(&Sq[bh * 64 + t], sAq[0][t] + sAq[1][t] + sAq[2][t] + sAq[3][t]);
    atomicAdd(&Sk[bh * 64 + t], sAk[0][t] + sAk[1][t] + sAk[2][t] + sAk[3][t]);
  }
}

// ---------------- K45: split-K kv partials (NO atomics), ev inline ----------------
__global__ __launch_bounds__(256) void k45_kv(const float* __restrict__ kk_,
      const float* __restrict__ vv, const float* __restrict__ Sq,
      float* __restrict__ kvpart, float* __restrict__ zpart) {
  const int bh = blockIdx.x;
  const int y = blockIdx.y;                       // KV_SPLIT slices
  constexpr int ROWS = cN / KV_SPLIT;             // 256
  const int n0 = y * ROWS;
  const int t = threadIdx.x;
  const int d = t & 63, eb = t >> 6;
  const int g = t >> 4, j = t & 15;               // 16 ev-groups of 16 lanes
  const int sr = t >> 4, sc = (t & 15) * 4;       // stage mapping
  const float* kb = kk_ + (size_t)bh * cN * cD;
  const float* vb = vv + (size_t)bh * cN * cD;
  const float4 sq4 = *(const float4*)&Sq[bh * 64 + j * 4];
  const float SqE[4] = {sq4.x + kEPS, sq4.y + kEPS, sq4.z + kEPS, sq4.w + kEPS};
  __shared__ float ks[32][64];
  __shared__ float vs[32][64];
  __shared__ float evs[32];
  __shared__ float zl[16];
  float acc[16] = {};
  float zacc = 0.f;
  float4 pk0 = *(const float4*)&kb[(size_t)(n0 + sr) * cD + sc];
  float4 pk1 = *(const float4*)&kb[(size_t)(n0 + 16 + sr) * cD + sc];
  float4 pv0 = *(const float4*)&vb[(size_t)(n0 + sr) * cD + sc];
  float4 pv1 = *(const float4*)&vb[(size_t)(n0 + 16 + sr) * cD + sc];
  for (int c0 = 0; c0 < ROWS; c0 += 32) {
    __syncthreads();
    *(float4*)&ks[sr][sc]      = pk0;
    *(float4*)&ks[sr + 16][sc] = pk1;
    *(float4*)&vs[sr][sc]      = pv0;
    *(float4*)&vs[sr + 16][sc] = pv1;
    __syncthreads();
    if (c0 + 32 < ROWS) {
      pk0 = *(const float4*)&kb[(size_t)(n0 + c0 + 32 + sr) * cD + sc];
      pk1 = *(const float4*)&kb[(size_t)(n0 + c0 + 48 + sr) * cD + sc];
      pv0 = *(const float4*)&vb[(size_t)(n0 + c0 + 32 + sr) * cD + sc];
      pv1 = *(const float4*)&vb[(size_t)(n0 + c0 + 48 + sr) * cD + sc];
    }
    #pragma unroll
    for (int rr = 0; rr < 2; ++rr) {
      const int r = g * 2 + rr;
      const float4 kk4 = *(const float4*)&ks[r][j * 4];
      float tt = 0.f;
      tt = fmaf(kk4.x + kEPS, SqE[0], tt);
      tt = fmaf(kk4.y + kEPS, SqE[1], tt);
      tt = fmaf(kk4.z + kEPS, SqE[2], tt);
      tt = fmaf(kk4.w + kEPS, SqE[3], tt);
      #pragma unroll
      for (int off = 1; off < 16; off <<= 1) tt += __shfl_xor(tt, off);
      if (j == 0) {
        const float cs = fminf(fmaxf(tt + kEPS, -1.f), 1.f);
        const float e = __expf(cs);
        evs[r] = e;
        zacc += e;
      }
    }
    __syncthreads();
    #pragma unroll
    for (int r = 0; r < 32; ++r) {
      const float kd = ks[r][d] * evs[r];
      #pragma unroll
      for (int j2 = 0; j2 < 16; ++j2)
        acc[j2] = fmaf(kd, vs[r][eb * 16 + j2], acc[j2]);
    }
  }
  if (j == 0) zl[g] = zacc;
  __syncthreads();
  if (t == 0) {
    float z = 0.f;
    #pragma unroll
    for (int i = 0; i < 16; ++i) z += zl[i];
    zpart[y * cBH + bh] = z;
  }
  float* kvb = kvpart + ((size_t)y * cBH + bh) * 4096 + d * 64 + eb * 16;
  #pragma unroll
  for (int j2 = 0; j2 < 16; ++j2) kvb[j2] = acc[j2];
}

// ---------------- K5R: fold split-K partials -> kvm, Zb (deterministic) ----------------
__global__ __launch_bounds__(256) void k5r_reduce(const float* __restrict__ kvpart,
      const float* __restrict__ zpart, float* __restrict__ kvm, float* __restrict__ Zb) {
  const int bh = blockIdx.x;
  const int t = threadIdx.x;
  for (int i = t; i < 4096; i += 256) {
    float s = 0.f;
    #pragma unroll
    for (int yy = 0; yy < KV_SPLIT; ++yy)
      s += kvpart[((size_t)yy * cBH + bh) * 4096 + i];
    kvm[(size_t)bh * 4096 + i] = s;
  }
  if (t == 0) {
    float z = 0.f;
    #pragma unroll
    for (int yy = 0; yy < KV_SPLIT; ++yy) z += zpart[yy * cBH + bh];
    Zb[bh] = z;
  }
}

// ---------------- K6b: xu = (q @ kv*(N/Z)) * si * sa -> split bf16 [M][512] ----------------
__global__ __launch_bounds__(256) void k6b_xu(const float* __restrict__ q,
      const float* __restrict__ kvmat, const float* __restrict__ si,
      const float* __restrict__ Sk, const float* __restrict__ Zb,
      ushort* __restrict__ xh, ushort* __restrict__ xl) {
  const int bh = blockIdx.x;
  const int b = bh >> 3, head = bh & 7;
  const int n0 = blockIdx.y * 64;
  const int lane = threadIdx.x & 63;
  const int wave = threadIdx.x >> 6;
  __shared__ float kvs[64][64];
  const float zs = (float)cN / Zb[bh];
  for (int i = threadIdx.x; i < 4096; i += 256)
    kvs[i >> 6][i & 63] = kvmat[(size_t)bh * 4096 + i] * zs;
  const float SkE = Sk[bh * 64 + lane] + kEPS;
  __syncthreads();
  const float* qb = q + (size_t)bh * cN * cD;
  for (int i = 0; i < 16; ++i) {
    const int n = n0 + wave * 16 + i;
    const float qd = qb[(size_t)n * cD + lane];
    float t2 = (qd + kEPS) * SkE;
    #pragma unroll
    for (int off = 1; off < 64; off <<= 1) t2 += __shfl_xor(t2, off);
    const float sa_n = 1.f / (1.f + __expf(-(t2 + kEPS)));
    float a0 = 0.f, a1 = 0.f, a2 = 0.f, a3 = 0.f;
    #pragma unroll
    for (int dd = 0; dd < 64; dd += 4) {
      a0 = fmaf(__shfl(qd, dd),     kvs[dd][lane],     a0);
      a1 = fmaf(__shfl(qd, dd + 1), kvs[dd + 1][lane], a1);
      a2 = fmaf(__shfl(qd, dd + 2), kvs[dd + 2][lane], a2);
      a3 = fmaf(__shfl(qd, dd + 3), kvs[dd + 3][lane], a3);
    }
    const float s = si[(size_t)bh * cN + n] * sa_n;
    const float val = ((a0 + a1) + (a2 + a3)) * s;
    ushort hbits, lbits;
    split2(val, hbits, lbits);
    const size_t m = (size_t)b * cN + n;
    xh[m * cC + head * 64 + lane] = hbits;
    xl[m * cC + head * 64 + lane] = lbits;
  }
}

extern "C" void kernel_launch(void* const* d_in, const int* in_sizes, int n_in,
                              void* d_out, int out_size, void* d_ws, size_t ws_size,
                              hipStream_t stream) {
  (void)in_sizes; (void)n_in; (void)out_size;
  const float* x     = (const float*)d_in[0];
  const float* Wqkv  = (const float*)d_in[1];
  const float* Wproj = (const float*)d_in[2];
  const float* bproj = (const float*)d_in[3];
  float* out = (float*)d_out;
  float* ws  = (float*)d_ws;

  const size_t SLAB = (size_t)cBH * cN * cD;       // 16,777,216 floats (64 MB)
  const size_t OFF_Q   = 0;
  const size_t OFF_K   = SLAB;
  const size_t OFF_V   = 2 * SLAB;                 // xu hi/lo alias v (dead after K45)
  const size_t OFF_ACC = 3 * SLAB;
  const size_t ACC_FLOATS = 2048 * 4 + 32 + (size_t)cBH * cD * cD;  // 139,296
  const size_t OFF_R   = OFF_ACC + ACC_FLOATS;     // time-shared region
  const size_t R_FLOATS = (size_t)3 * cHD * cC;    // wq hi+lo is the largest user
  const size_t TOTAL   = OFF_R + R_FLOATS;         // ~208.2 MB (proven fit)
  if (ws_size < TOTAL * sizeof(float)) return;

  float* q    = ws + OFF_Q;
  float* k    = ws + OFF_K;
  float* v    = ws + OFF_V;
  float* ksum = ws + OFF_ACC;
  float* qsum = ksum + 2048;
  float* Sk   = ksum + 4096;
  float* Sq   = ksum + 6144;
  float* Zb   = ksum + 8192;
  float* kvm  = ksum + 8224;

  // region R timeline: wq [split->gemm0] ; si [k34->k6b] ; wp [split->gemm1]
  ushort* wqh = (ushort*)(ws + OFF_R);
  ushort* wql = wqh + (size_t)3 * cHD * cC;
  float*  si  = ws + OFF_R;
  ushort* wph = (ushort*)(ws + OFF_R);
  ushort* wpl = wph + (size_t)cC * cHD;

  // xu bf16 hi/lo overlay the v slab (v dead after K45)
  ushort* xh = (ushort*)(ws + OFF_V);
  ushort* xl = xh + (size_t)cM * cHD;

  // k45 split-K partials live in d_out (only gemm1 writes d_out, at the end)
  float* kvpart = out;                                   // 16 MB
  float* zpart  = out + (size_t)KV_SPLIT * cBH * 4096;   // 1024 floats

  hipMemsetAsync(ksum, 0, ACC_FLOATS * sizeof(float), stream);

  split_w<<<(3 * cHD * cC / 4 + 255) / 256, 256, 0, stream>>>(Wqkv, wqh, wql, 3 * cHD * cC / 4);
  gemm_mfma<0, 12><<<dim3(cM / 128, (3 * cHD) / 128), 256, 0, stream>>>(
      x, nullptr, nullptr, wqh, wql, nullptr, q, k, v, qsum, ksum);
  k34_flow<<<dim3(cBH, cN / 256), 256, 0, stream>>>(q, k, qsum, ksum, si, Sq, Sk);
  k45_kv<<<dim3(cBH, KV_SPLIT), 256, 0, stream>>>(k, v, Sq, kvpart, zpart);
  k5r_reduce<<<cBH, 256, 0, stream>>>(kvpart, zpart, kvm, Zb);
  k6b_xu<<<dim3(cBH, cN / 64), 256, 0, stream>>>(q, kvm, si, Sk, Zb, xh, xl);
  split_w<<<(cC * cHD / 4 + 255) / 256, 256, 0, stream>>>(Wproj, wph, wpl, cC * cHD / 4);
  gemm_mfma<1, 4><<<dim3(cM / 128, cHD / 128), 256, 0, stream>>>(
      nullptr, xh, xl, wph, wpl, bproj, out, nullptr, nullptr, nullptr, nullptr);
}

// Round 8
// 536.973 us; speedup vs baseline: 1.1301x; 1.1301x over previous
//
#include <hip/hip_runtime.h>
#include <hip/hip_bf16.h>

typedef __attribute__((ext_vector_type(8))) short short8;
typedef __attribute__((ext_vector_type(4))) float f32x4;

constexpr int cB = 4, cN = 8192, cC = 512, cH = 8, cD = 64;
constexpr int cM = cB * cN;        // 32768 tokens
constexpr int cHD = cH * cD;       // 512
constexpr int cBH = cB * cH;       // 32
constexpr float kEPS = 1e-6f;
constexpr int KV_SPLIT = 32;       // k45 split-K slices

// ---- split f32 -> (bf16 hi by truncation, bf16 lo of remainder) ----
__device__ __forceinline__ void split2(float f, ushort& h, ushort& l) {
  unsigned u = __float_as_uint(f);
  h = (ushort)(u >> 16);
  float fl = f - __uint_as_float(u & 0xffff0000u);
  l = (ushort)(__float_as_uint(fl) >> 16);
}
__device__ __forceinline__ int pack_hi(float a, float b) {
  return (int)((__float_as_uint(a) >> 16) | (__float_as_uint(b) & 0xffff0000u));
}
__device__ __forceinline__ int pack_lo(float a, float b) {
  float la = a - __uint_as_float(__float_as_uint(a) & 0xffff0000u);
  float lb = b - __uint_as_float(__float_as_uint(b) & 0xffff0000u);
  return (int)((__float_as_uint(la) >> 16) | (__float_as_uint(lb) & 0xffff0000u));
}

// ---------------- splitter: f32 -> bf16 hi/lo (weights only) ----------------
__global__ __launch_bounds__(256) void split_w(const float* __restrict__ src,
    ushort* __restrict__ hi, ushort* __restrict__ lo, int n4) {
  int i = blockIdx.x * 256 + threadIdx.x;
  if (i >= n4) return;
  float4 v = reinterpret_cast<const float4*>(src)[i];
  ushort4 h, l;
  split2(v.x, h.x, l.x); split2(v.y, h.y, l.y);
  split2(v.z, h.z, l.z); split2(v.w, h.w, l.w);
  reinterpret_cast<ushort4*>(hi)[i] = h;
  reinterpret_cast<ushort4*>(lo)[i] = l;
}

// ---------------- split-bf16 MFMA GEMM: C = A[Mx512] @ W[NCx512]^T ----------------
// Single-buffer LDS (32 KB -> 4 blocks/CU), 2 barriers/K-step.
// A-reg prefetch for tile kt+1 issued AFTER the stage barrier -> overlaps MFMA.
// All LDS tiles XOR-unit-swizzled (both-sides involution, zero conflicts).
// Bijective XCD-chunked block swizzle (T1), y-fastest decode (A-panel L2 reuse).
// EPI=0: A f32 reg-staged+converted. Epilogue: qkv scatter + fused qsum/ksum.
// EPI=1: A pre-split bf16 via global_load_lds. Epilogue: out + bias.
// NOTE (r7 lesson): weights/operands must NEVER live in d_out for the kernel
// that writes d_out — intra-kernel read/write race. All gemm1 inputs are in ws.
template<int EPI, int NY>
__global__ __launch_bounds__(256) void gemm_mfma(
    const float* __restrict__ A,
    const ushort* __restrict__ Ah_g, const ushort* __restrict__ Al_g,
    const ushort* __restrict__ Wh, const ushort* __restrict__ Wl,
    const float* __restrict__ bias,
    float* __restrict__ o0, float* __restrict__ o1, float* __restrict__ o2,
    float* __restrict__ qsum, float* __restrict__ ksum) {
  constexpr bool AF32 = (EPI == 0);
  constexpr int NT = cC / 32;                   // 16 K-steps of BK=32
  __shared__ ushort AhS[128 * 32], AlS[128 * 32];
  __shared__ ushort BhS[128 * 32], BlS[128 * 32];
  __shared__ float colsum[128];
  const int t = threadIdx.x;
  const int wave = t >> 6, lane = t & 63;
  const int wm = wave >> 1, wn = wave & 1;      // 2x2 waves of 64x64
  const int l15 = lane & 15, lg = lane >> 4;

  // ---- XCD-chunked bijective swizzle (nwg % 8 == 0 for both launches) ----
  const int raw = blockIdx.y * gridDim.x + blockIdx.x;
  const int q8 = (int)(gridDim.x * NY) >> 3;
  const int wg2 = (raw & 7) * q8 + (raw >> 3);
  const int rowchunk = wg2 / NY, ycol = wg2 - rowchunk * NY;
  const int row0 = rowchunk * 128, col0 = ycol * 128;

  if (EPI == 0 && t < 128) colsum[t] = 0.f;     // ordered by loop barriers

  f32x4 acc[4][4] = {};

  const int srow = lane >> 2, sunit = lane & 3; // bf16 gld_lds stage mapping
  const int arow = t >> 1, akh = (t & 1) * 16;  // A f32 reg-stage mapping
  const float* aptr = AF32 ? (A + (size_t)(row0 + arow) * cC + akh) : nullptr;
  const int akey = (arow >> 1) & 3;
  const int au0 = (t & 1) * 2;

  float4 pa0, pa1, pa2, pa3;                    // A prefetch regs (EPI=0)

#define STAGE_B(k0)                                                             \
  _Pragma("unroll")                                                             \
  for (int hh = 0; hh < 2; ++hh) {                                              \
    const int br = wave * 32 + hh * 16 + srow;                                  \
    const int sw = sunit ^ ((br >> 1) & 3);                                     \
    const size_t goff = (size_t)(col0 + br) * cC + (k0) + sw * 8;               \
    __builtin_amdgcn_global_load_lds(                                           \
        (const __attribute__((address_space(1))) void*)(Wh + goff),             \
        (__attribute__((address_space(3))) void*)(&BhS[(wave * 32 + hh * 16) * 32]), \
        16, 0, 0);                                                              \
    __builtin_amdgcn_global_load_lds(                                           \
        (const __attribute__((address_space(1))) void*)(Wl + goff),             \
        (__attribute__((address_space(3))) void*)(&BlS[(wave * 32 + hh * 16) * 32]), \
        16, 0, 0);                                                              \
  }

#define STAGE_A_PRE(k0)                                                         \
  _Pragma("unroll")                                                             \
  for (int hh = 0; hh < 2; ++hh) {                                              \
    const int ar = wave * 32 + hh * 16 + srow;                                  \
    const int sw = sunit ^ ((ar >> 1) & 3);                                     \
    const size_t goff = (size_t)(row0 + ar) * cC + (k0) + sw * 8;               \
    __builtin_amdgcn_global_load_lds(                                           \
        (const __attribute__((address_space(1))) void*)(Ah_g + goff),           \
        (__attribute__((address_space(3))) void*)(&AhS[(wave * 32 + hh * 16) * 32]), \
        16, 0, 0);                                                              \
    __builtin_amdgcn_global_load_lds(                                           \
        (const __attribute__((address_space(1))) void*)(Al_g + goff),           \
        (__attribute__((address_space(3))) void*)(&AlS[(wave * 32 + hh * 16) * 32]), \
        16, 0, 0);                                                              \
  }

#define LOAD_A_REGS(k0)                                                         \
  pa0 = *(const float4*)(aptr + (k0) + 0);                                      \
  pa1 = *(const float4*)(aptr + (k0) + 4);                                      \
  pa2 = *(const float4*)(aptr + (k0) + 8);                                      \
  pa3 = *(const float4*)(aptr + (k0) + 12);

#define CONVERT_WRITE_A()                                                       \
  {                                                                             \
    int4 H0 = make_int4(pack_hi(pa0.x, pa0.y), pack_hi(pa0.z, pa0.w),           \
                        pack_hi(pa1.x, pa1.y), pack_hi(pa1.z, pa1.w));          \
    int4 H1 = make_int4(pack_hi(pa2.x, pa2.y), pack_hi(pa2.z, pa2.w),           \
                        pack_hi(pa3.x, pa3.y), pack_hi(pa3.z, pa3.w));          \
    int4 L0 = make_int4(pack_lo(pa0.x, pa0.y), pack_lo(pa0.z, pa0.w),           \
                        pack_lo(pa1.x, pa1.y), pack_lo(pa1.z, pa1.w));          \
    int4 L1 = make_int4(pack_lo(pa2.x, pa2.y), pack_lo(pa2.z, pa2.w),           \
                        pack_lo(pa3.x, pa3.y), pack_lo(pa3.z, pa3.w));          \
    *(int4*)&AhS[arow * 32 + ((au0 + 0) ^ akey) * 8] = H0;                      \
    *(int4*)&AhS[arow * 32 + ((au0 + 1) ^ akey) * 8] = H1;                      \
    *(int4*)&AlS[arow * 32 + ((au0 + 0) ^ akey) * 8] = L0;                      \
    *(int4*)&AlS[arow * 32 + ((au0 + 1) ^ akey) * 8] = L1;                      \
  }

  if (AF32) { LOAD_A_REGS(0); }

  for (int kt = 0; kt < NT; ++kt) {
    // ---- stage tile kt into LDS ----
    if (AF32) CONVERT_WRITE_A()
    else      STAGE_A_PRE(kt * 32);
    STAGE_B(kt * 32);
    __syncthreads();
    // ---- next-tile A loads fly under the MFMA block ----
    if (AF32 && kt + 1 < NT) { LOAD_A_REGS((kt + 1) * 32); }
    // ---- fragments + 3-product MFMA ----
    short8 ah[4], al[4];
    #pragma unroll
    for (int mi = 0; mi < 4; ++mi) {
      const int r = wm * 64 + mi * 16 + l15;
      const int aidx = r * 32 + (lg ^ ((r >> 1) & 3)) * 8;
      ah[mi] = *reinterpret_cast<const short8*>(&AhS[aidx]);
      al[mi] = *reinterpret_cast<const short8*>(&AlS[aidx]);
    }
    #pragma unroll
    for (int ni = 0; ni < 4; ++ni) {
      const int c = wn * 64 + ni * 16 + l15;
      const int bidx = c * 32 + (lg ^ ((c >> 1) & 3)) * 8;
      const short8 bh = *reinterpret_cast<const short8*>(&BhS[bidx]);
      const short8 bl = *reinterpret_cast<const short8*>(&BlS[bidx]);
      #pragma unroll
      for (int mi = 0; mi < 4; ++mi) {
        acc[mi][ni] = __builtin_amdgcn_mfma_f32_16x16x32_bf16(ah[mi], bh, acc[mi][ni], 0, 0, 0);
        acc[mi][ni] = __builtin_amdgcn_mfma_f32_16x16x32_bf16(al[mi], bh, acc[mi][ni], 0, 0, 0);
        acc[mi][ni] = __builtin_amdgcn_mfma_f32_16x16x32_bf16(ah[mi], bl, acc[mi][ni], 0, 0, 0);
      }
    }
    __syncthreads();                           // MFMA reads done before overwrite
  }
#undef STAGE_B
#undef STAGE_A_PRE
#undef LOAD_A_REGS
#undef CONVERT_WRITE_A

  // ---- epilogue: C/D map col=lane&15, row=(lane>>4)*4+r ----
  const bool qk_block = (EPI == 0) && (ycol < 8);
  float csum[4] = {};
  #pragma unroll
  for (int mi = 0; mi < 4; ++mi) {
    #pragma unroll
    for (int ni = 0; ni < 4; ++ni) {
      const int col = col0 + wn * 64 + ni * 16 + l15;
      #pragma unroll
      for (int r = 0; r < 4; ++r) {
        const int m = row0 + wm * 64 + mi * 16 + lg * 4 + r;
        const float val = acc[mi][ni][r];
        if (EPI == 0) {
          const int which = col >> 9;
          const int c2 = col & 511;
          const int h = c2 >> 6, d = c2 & 63;
          const int bb = m >> 13, n = m & 8191;
          const size_t idx = (((size_t)(bb * cH + h)) * cN + n) * cD + d;
          if (which < 2) {
            const float sv = 1.f / (1.f + __expf(-val));
            if (which == 0) o0[idx] = sv; else o1[idx] = sv;
            csum[ni] += sv;
          } else {
            o2[idx] = val * 0.125f;
          }
        } else {
          o0[(size_t)m * cC + col] = val + bias[col];
        }
      }
    }
  }
  if (qk_block) {
    #pragma unroll
    for (int ni = 0; ni < 4; ++ni)
      atomicAdd(&colsum[wn * 64 + ni * 16 + l15], csum[ni]);
    __syncthreads();
    if (t < 128) {
      const int col = col0 + t;
      const int c2 = col & 511;
      const int h = c2 >> 6, d = c2 & 63;
      const int bb = row0 >> 13;
      float* tgt = (col < 512) ? qsum : ksum;
      atomicAdd(&tgt[(bb * cH + h) * cD + d], colsum[t]);
    }
  }
}

// ---------------- K34: si, so; accumulate Sq, Sk (4 rows/wave/iter, float4) ----------------
__global__ __launch_bounds__(256) void k34_flow(const float* __restrict__ q,
      const float* __restrict__ k, const float* __restrict__ qsum,
      const float* __restrict__ ksum, float* __restrict__ si,
      float* __restrict__ Sq, float* __restrict__ Sk) {
  const int bh = blockIdx.x;
  const int n0 = blockIdx.y * 256;
  const int t = threadIdx.x;
  const int wave = t >> 6, lane = t & 63;
  const int g = lane >> 4, j = lane & 15;
  const float* qb = q + (size_t)bh * cN * cD;
  const float* kb = k + (size_t)bh * cN * cD;
  const float4 ks4 = *(const float4*)&ksum[bh * 64 + j * 4];
  const float4 qs4 = *(const float4*)&qsum[bh * 64 + j * 4];
  const float ksd[4] = {ks4.x + kEPS, ks4.y + kEPS, ks4.z + kEPS, ks4.w + kEPS};
  const float qsd[4] = {qs4.x + kEPS, qs4.y + kEPS, qs4.z + kEPS, qs4.w + kEPS};
  float aSq[4] = {}, aSk[4] = {};
  for (int i = 0; i < 16; ++i) {
    const int n = n0 + wave * 64 + i * 4 + g;
    const float4 q4 = *(const float4*)&qb[(size_t)n * cD + j * 4];
    const float4 k4 = *(const float4*)&kb[(size_t)n * cD + j * 4];
    const float qa[4] = {q4.x, q4.y, q4.z, q4.w};
    const float ka[4] = {k4.x, k4.y, k4.z, k4.w};
    float t1 = 0.f, t2 = 0.f;
    #pragma unroll
    for (int c = 0; c < 4; ++c) {
      t1 = fmaf(qa[c] + kEPS, ksd[c], t1);
      t2 = fmaf(ka[c] + kEPS, qsd[c], t2);
    }
    #pragma unroll
    for (int off = 1; off < 16; off <<= 1) {
      t1 += __shfl_xor(t1, off);
      t2 += __shfl_xor(t2, off);
    }
    const float si_n = 1.f / (t1 + kEPS);
    const float so_n = 1.f / (t2 + kEPS);
    if (j == 0) si[(size_t)bh * cN + n] = si_n;
    #pragma unroll
    for (int c = 0; c < 4; ++c) {
      aSq[c] = fmaf(qa[c], si_n, aSq[c]);
      aSk[c] = fmaf(ka[c], so_n, aSk[c]);
    }
  }
  #pragma unroll
  for (int c = 0; c < 4; ++c) {
    aSq[c] += __shfl_xor(aSq[c], 16); aSq[c] += __shfl_xor(aSq[c], 32);
    aSk[c] += __shfl_xor(aSk[c], 16); aSk[c] += __shfl_xor(aSk[c], 32);
  }
  __shared__ float sAq[4][64], sAk[4][64];
  if (g == 0) {
    #pragma unroll
    for (int c = 0; c < 4; ++c) { sAq[wave][j * 4 + c] = aSq[c]; sAk[wave][j * 4 + c] = aSk[c]; }
  }
  __syncthreads();
  if (t < 64) {
    atomicAdd(&Sq[bh * 64 + t], sAq[0][t] + sAq[1][t] + sAq[2][t] + sAq[3][t]);
    atomicAdd(&Sk[bh * 64 + t], sAk[0][t] + sAk[1][t] + sAk[2][t] + sAk[3][t]);
  }
}

// ---------------- K45: split-K kv partials (NO atomics), ev inline ----------------
__global__ __launch_bounds__(256) void k45_kv(const float* __restrict__ kk_,
      const float* __restrict__ vv, const float* __restrict__ Sq,
      float* __restrict__ kvpart, float* __restrict__ zpart) {
  const int bh = blockIdx.x;
  const int y = blockIdx.y;                       // KV_SPLIT slices
  constexpr int ROWS = cN / KV_SPLIT;             // 256
  const int n0 = y * ROWS;
  const int t = threadIdx.x;
  const int d = t & 63, eb = t >> 6;
  const int g = t >> 4, j = t & 15;               // 16 ev-groups of 16 lanes
  const int sr = t >> 4, sc = (t & 15) * 4;       // stage mapping
  const float* kb = kk_ + (size_t)bh * cN * cD;
  const float* vb = vv + (size_t)bh * cN * cD;
  const float4 sq4 = *(const float4*)&Sq[bh * 64 + j * 4];
  const float SqE[4] = {sq4.x + kEPS, sq4.y + kEPS, sq4.z + kEPS, sq4.w + kEPS};
  __shared__ float ks[32][64];
  __shared__ float vs[32][64];
  __shared__ float evs[32];
  __shared__ float zl[16];
  float acc[16] = {};
  float zacc = 0.f;
  float4 pk0 = *(const float4*)&kb[(size_t)(n0 + sr) * cD + sc];
  float4 pk1 = *(const float4*)&kb[(size_t)(n0 + 16 + sr) * cD + sc];
  float4 pv0 = *(const float4*)&vb[(size_t)(n0 + sr) * cD + sc];
  float4 pv1 = *(const float4*)&vb[(size_t)(n0 + 16 + sr) * cD + sc];
  for (int c0 = 0; c0 < ROWS; c0 += 32) {
    __syncthreads();
    *(float4*)&ks[sr][sc]      = pk0;
    *(float4*)&ks[sr + 16][sc] = pk1;
    *(float4*)&vs[sr][sc]      = pv0;
    *(float4*)&vs[sr + 16][sc] = pv1;
    __syncthreads();
    if (c0 + 32 < ROWS) {
      pk0 = *(const float4*)&kb[(size_t)(n0 + c0 + 32 + sr) * cD + sc];
      pk1 = *(const float4*)&kb[(size_t)(n0 + c0 + 48 + sr) * cD + sc];
      pv0 = *(const float4*)&vb[(size_t)(n0 + c0 + 32 + sr) * cD + sc];
      pv1 = *(const float4*)&vb[(size_t)(n0 + c0 + 48 + sr) * cD + sc];
    }
    #pragma unroll
    for (int rr = 0; rr < 2; ++rr) {
      const int r = g * 2 + rr;
      const float4 kk4 = *(const float4*)&ks[r][j * 4];
      float tt = 0.f;
      tt = fmaf(kk4.x + kEPS, SqE[0], tt);
      tt = fmaf(kk4.y + kEPS, SqE[1], tt);
      tt = fmaf(kk4.z + kEPS, SqE[2], tt);
      tt = fmaf(kk4.w + kEPS, SqE[3], tt);
      #pragma unroll
      for (int off = 1; off < 16; off <<= 1) tt += __shfl_xor(tt, off);
      if (j == 0) {
        const float cs = fminf(fmaxf(tt + kEPS, -1.f), 1.f);
        const float e = __expf(cs);
        evs[r] = e;
        zacc += e;
      }
    }
    __syncthreads();
    #pragma unroll
    for (int r = 0; r < 32; ++r) {
      const float kd = ks[r][d] * evs[r];
      #pragma unroll
      for (int j2 = 0; j2 < 16; ++j2)
        acc[j2] = fmaf(kd, vs[r][eb * 16 + j2], acc[j2]);
    }
  }
  if (j == 0) zl[g] = zacc;
  __syncthreads();
  if (t == 0) {
    float z = 0.f;
    #pragma unroll
    for (int i = 0; i < 16; ++i) z += zl[i];
    zpart[y * cBH + bh] = z;
  }
  float* kvb = kvpart + ((size_t)y * cBH + bh) * 4096 + d * 64 + eb * 16;
  #pragma unroll
  for (int j2 = 0; j2 < 16; ++j2) kvb[j2] = acc[j2];
}

// ---------------- K5R: fold split-K partials -> kvm, Zb (deterministic) ----------------
__global__ __launch_bounds__(256) void k5r_reduce(const float* __restrict__ kvpart,
      const float* __restrict__ zpart, float* __restrict__ kvm, float* __restrict__ Zb) {
  const int bh = blockIdx.x;
  const int yq = blockIdx.y;                      // 4 chunks of 1024
  const int t = threadIdx.x;
  for (int i = yq * 1024 + t; i < (yq + 1) * 1024; i += 256) {
    float s = 0.f;
    #pragma unroll
    for (int yy = 0; yy < KV_SPLIT; ++yy)
      s += kvpart[((size_t)yy * cBH + bh) * 4096 + i];
    kvm[(size_t)bh * 4096 + i] = s;
  }
  if (yq == 0 && t == 0) {
    float z = 0.f;
    #pragma unroll
    for (int yy = 0; yy < KV_SPLIT; ++yy) z += zpart[yy * cBH + bh];
    Zb[bh] = z;
  }
}

// ---------------- K6b: xu = (q @ kv*(N/Z)) * si * sa -> split bf16 [M][512] ----------------
__global__ __launch_bounds__(256) void k6b_xu(const float* __restrict__ q,
      const float* __restrict__ kvmat, const float* __restrict__ si,
      const float* __restrict__ Sk, const float* __restrict__ Zb,
      ushort* __restrict__ xh, ushort* __restrict__ xl) {
  const int bh = blockIdx.x;
  const int b = bh >> 3, head = bh & 7;
  const int n0 = blockIdx.y * 64;
  const int lane = threadIdx.x & 63;
  const int wave = threadIdx.x >> 6;
  __shared__ float kvs[64][64];
  const float zs = (float)cN / Zb[bh];
  for (int i = threadIdx.x; i < 4096; i += 256)
    kvs[i >> 6][i & 63] = kvmat[(size_t)bh * 4096 + i] * zs;
  const float SkE = Sk[bh * 64 + lane] + kEPS;
  __syncthreads();
  const float* qb = q + (size_t)bh * cN * cD;
  for (int i = 0; i < 16; ++i) {
    const int n = n0 + wave * 16 + i;
    const float qd = qb[(size_t)n * cD + lane];
    float t2 = (qd + kEPS) * SkE;
    #pragma unroll
    for (int off = 1; off < 64; off <<= 1) t2 += __shfl_xor(t2, off);
    const float sa_n = 1.f / (1.f + __expf(-(t2 + kEPS)));
    float a0 = 0.f, a1 = 0.f, a2 = 0.f, a3 = 0.f;
    #pragma unroll
    for (int dd = 0; dd < 64; dd += 4) {
      a0 = fmaf(__shfl(qd, dd),     kvs[dd][lane],     a0);
      a1 = fmaf(__shfl(qd, dd + 1), kvs[dd + 1][lane], a1);
      a2 = fmaf(__shfl(qd, dd + 2), kvs[dd + 2][lane], a2);
      a3 = fmaf(__shfl(qd, dd + 3), kvs[dd + 3][lane], a3);
    }
    const float s = si[(size_t)bh * cN + n] * sa_n;
    const float val = ((a0 + a1) + (a2 + a3)) * s;
    ushort hbits, lbits;
    split2(val, hbits, lbits);
    const size_t m = (size_t)b * cN + n;
    xh[m * cC + head * 64 + lane] = hbits;
    xl[m * cC + head * 64 + lane] = lbits;
  }
}

extern "C" void kernel_launch(void* const* d_in, const int* in_sizes, int n_in,
                              void* d_out, int out_size, void* d_ws, size_t ws_size,
                              hipStream_t stream) {
  (void)in_sizes; (void)n_in; (void)out_size;
  const float* x     = (const float*)d_in[0];
  const float* Wqkv  = (const float*)d_in[1];
  const float* Wproj = (const float*)d_in[2];
  const float* bproj = (const float*)d_in[3];
  float* out = (float*)d_out;
  float* ws  = (float*)d_ws;

  const size_t SLAB = (size_t)cBH * cN * cD;       // 16,777,216 floats (64 MB)
  const size_t OFF_Q   = 0;
  const size_t OFF_K   = SLAB;
  const size_t OFF_V   = 2 * SLAB;                 // xu hi/lo alias v (dead after K45)
  const size_t OFF_ACC = 3 * SLAB;
  const size_t ACC_FLOATS = 2048 * 4 + 32 + (size_t)cBH * cD * cD;  // 139,296
  const size_t OFF_R   = OFF_ACC + ACC_FLOATS;     // time-shared region
  const size_t R_FLOATS = (size_t)3 * cHD * cC;    // 786,432 floats
  const size_t TOTAL   = OFF_R + R_FLOATS;         // ~208.2 MB (proven fit r2-r6)
  if (ws_size < TOTAL * sizeof(float)) return;

  float* q    = ws + OFF_Q;
  float* k    = ws + OFF_K;
  float* v    = ws + OFF_V;
  float* ksum = ws + OFF_ACC;
  float* qsum = ksum + 2048;
  float* Sk   = ksum + 4096;
  float* Sq   = ksum + 6144;
  float* Zb   = ksum + 8192;
  float* kvm  = ksum + 8224;

  // region R timeline (786,432 floats):
  //   [0 .. 786432)        wq hi+lo     alive: split_w(wq) -> gemm0
  //   [0 .. 262144)        si           alive: k34 -> k6b      (after gemm0)
  //   [262144 .. 524288)   wp hi+lo     alive: split_w(wp) -> gemm1 (after gemm0)
  ushort* wqh = (ushort*)(ws + OFF_R);
  ushort* wql = wqh + (size_t)3 * cHD * cC;
  float*  si  = ws + OFF_R;
  ushort* wph = (ushort*)(ws + OFF_R + (size_t)cBH * cN);   // +262144 floats
  ushort* wpl = wph + (size_t)cC * cHD;

  // xu bf16 hi/lo overlay the v slab (v dead after K45)
  ushort* xh = (ushort*)(ws + OFF_V);
  ushort* xl = xh + (size_t)cM * cHD;

  // k45 split-K partials in d_out are legal: their lifetime (k45 -> k5r) ends
  // before gemm1 (the d_out writer) starts. gemm1 must read NOTHING from d_out.
  float* kvpart = out;                                   // 16 MB
  float* zpart  = out + (size_t)KV_SPLIT * cBH * 4096;   // 1024 floats

  hipMemsetAsync(ksum, 0, ACC_FLOATS * sizeof(float), stream);

  split_w<<<(3 * cHD * cC / 4 + 255) / 256, 256, 0, stream>>>(Wqkv, wqh, wql, 3 * cHD * cC / 4);
  gemm_mfma<0, 12><<<dim3(cM / 128, (3 * cHD) / 128), 256, 0, stream>>>(
      x, nullptr, nullptr, wqh, wql, nullptr, q, k, v, qsum, ksum);
  split_w<<<(cC * cHD / 4 + 255) / 256, 256, 0, stream>>>(Wproj, wph, wpl, cC * cHD / 4);
  k34_flow<<<dim3(cBH, cN / 256), 256, 0, stream>>>(q, k, qsum, ksum, si, Sq, Sk);
  k45_kv<<<dim3(cBH, KV_SPLIT), 256, 0, stream>>>(k, v, Sq, kvpart, zpart);
  k5r_reduce<<<dim3(cBH, 4), 256, 0, stream>>>(kvpart, zpart, kvm, Zb);
  k6b_xu<<<dim3(cBH, cN / 64), 256, 0, stream>>>(q, kvm, si, Sk, Zb, xh, xl);
  gemm_mfma<1, 4><<<dim3(cM / 128, cHD / 128), 256, 0, stream>>>(
      nullptr, xh, xl, wph, wpl, bproj, out, nullptr, nullptr, nullptr, nullptr);
}

// Round 9
// 493.854 us; speedup vs baseline: 1.2288x; 1.0873x over previous
//
#include <hip/hip_runtime.h>
#include <hip/hip_bf16.h>

typedef __attribute__((ext_vector_type(8))) short short8;
typedef __attribute__((ext_vector_type(4))) float f32x4;

constexpr int cB = 4, cN = 8192, cC = 512, cH = 8, cD = 64;
constexpr int cM = cB * cN;        // 32768 tokens
constexpr int cHD = cH * cD;       // 512
constexpr int cBH = cB * cH;       // 32
constexpr float kEPS = 1e-6f;
constexpr int KV_SPLIT = 32;       // k45 split-K slices

// ---- split f32 -> (bf16 hi by truncation, bf16 lo of remainder) — exact-A path ----
__device__ __forceinline__ void split2(float f, ushort& h, ushort& l) {
  unsigned u = __float_as_uint(f);
  h = (ushort)(u >> 16);
  float fl = f - __uint_as_float(u & 0xffff0000u);
  l = (ushort)(__float_as_uint(fl) >> 16);
}
__device__ __forceinline__ int pack_hi(float a, float b) {
  return (int)((__float_as_uint(a) >> 16) | (__float_as_uint(b) & 0xffff0000u));
}
__device__ __forceinline__ int pack_lo(float a, float b) {
  float la = a - __uint_as_float(__float_as_uint(a) & 0xffff0000u);
  float lb = b - __uint_as_float(__float_as_uint(b) & 0xffff0000u);
  return (int)((__float_as_uint(la) >> 16) | (__float_as_uint(lb) & 0xffff0000u));
}
// ---- RNE f32 -> bf16 (unbiased; for the single-bf16 weight operand) ----
__device__ __forceinline__ ushort rne_bf16(float f) {
  unsigned u = __float_as_uint(f);
  u += 0x7fffu + ((u >> 16) & 1u);
  return (ushort)(u >> 16);
}

// ---------------- weight rounder: f32 -> single bf16 (RNE) ----------------
__global__ __launch_bounds__(256) void round_w(const float* __restrict__ src,
    ushort* __restrict__ w, int n4) {
  int i = blockIdx.x * 256 + threadIdx.x;
  if (i >= n4) return;
  float4 v = reinterpret_cast<const float4*>(src)[i];
  ushort4 h;
  h.x = rne_bf16(v.x); h.y = rne_bf16(v.y);
  h.z = rne_bf16(v.z); h.w = rne_bf16(v.w);
  reinterpret_cast<ushort4*>(w)[i] = h;
}

// ---------------- 2-product MFMA GEMM: C = A[Mx512] @ W[NCx512]^T ----------------
// A exact (bf16 hi+lo), B = RNE-rounded single bf16. acc = Ah*B + Al*B (= A*B).
// Single-buffer LDS (24 KB -> 6 blocks/CU), 2 barriers/K-step.
// A-reg prefetch for tile kt+1 issued AFTER the stage barrier -> overlaps MFMA.
// All LDS tiles XOR-unit-swizzled (zero conflicts, r8-verified).
// Bijective XCD-chunked block swizzle, y-fastest decode (FETCH halved, r8-verified).
// EPI=0: A f32 reg-staged+converted. Epilogue: qkv scatter + fused qsum/ksum.
// EPI=1: A pre-split bf16 via global_load_lds. Epilogue: out + bias.
// NOTE (r7 lesson): gemm1 reads NOTHING from d_out (intra-kernel race).
template<int EPI, int NY>
__global__ __launch_bounds__(256) void gemm_mfma(
    const float* __restrict__ A,
    const ushort* __restrict__ Ah_g, const ushort* __restrict__ Al_g,
    const ushort* __restrict__ Wb,
    const float* __restrict__ bias,
    float* __restrict__ o0, float* __restrict__ o1, float* __restrict__ o2,
    float* __restrict__ qsum, float* __restrict__ ksum) {
  constexpr bool AF32 = (EPI == 0);
  constexpr int NT = cC / 32;                   // 16 K-steps of BK=32
  __shared__ ushort AhS[128 * 32], AlS[128 * 32];
  __shared__ ushort BhS[128 * 32];
  __shared__ float colsum[128];
  const int t = threadIdx.x;
  const int wave = t >> 6, lane = t & 63;
  const int wm = wave >> 1, wn = wave & 1;      // 2x2 waves of 64x64
  const int l15 = lane & 15, lg = lane >> 4;

  // ---- XCD-chunked bijective swizzle (nwg % 8 == 0 for both launches) ----
  const int raw = blockIdx.y * gridDim.x + blockIdx.x;
  const int q8 = (int)(gridDim.x * NY) >> 3;
  const int wg2 = (raw & 7) * q8 + (raw >> 3);
  const int rowchunk = wg2 / NY, ycol = wg2 - rowchunk * NY;
  const int row0 = rowchunk * 128, col0 = ycol * 128;

  if (EPI == 0 && t < 128) colsum[t] = 0.f;     // ordered by loop barriers

  f32x4 acc[4][4] = {};

  const int srow = lane >> 2, sunit = lane & 3; // bf16 gld_lds stage mapping
  const int arow = t >> 1, akh = (t & 1) * 16;  // A f32 reg-stage mapping
  const float* aptr = AF32 ? (A + (size_t)(row0 + arow) * cC + akh) : nullptr;
  const int akey = (arow >> 1) & 3;
  const int au0 = (t & 1) * 2;

  float4 pa0, pa1, pa2, pa3;                    // A prefetch regs (EPI=0)

#define STAGE_B(k0)                                                             \
  _Pragma("unroll")                                                             \
  for (int hh = 0; hh < 2; ++hh) {                                              \
    const int br = wave * 32 + hh * 16 + srow;                                  \
    const int sw = sunit ^ ((br >> 1) & 3);                                     \
    const size_t goff = (size_t)(col0 + br) * cC + (k0) + sw * 8;               \
    __builtin_amdgcn_global_load_lds(                                           \
        (const __attribute__((address_space(1))) void*)(Wb + goff),             \
        (__attribute__((address_space(3))) void*)(&BhS[(wave * 32 + hh * 16) * 32]), \
        16, 0, 0);                                                              \
  }

#define STAGE_A_PRE(k0)                                                         \
  _Pragma("unroll")                                                             \
  for (int hh = 0; hh < 2; ++hh) {                                              \
    const int ar = wave * 32 + hh * 16 + srow;                                  \
    const int sw = sunit ^ ((ar >> 1) & 3);                                     \
    const size_t goff = (size_t)(row0 + ar) * cC + (k0) + sw * 8;               \
    __builtin_amdgcn_global_load_lds(                                           \
        (const __attribute__((address_space(1))) void*)(Ah_g + goff),           \
        (__attribute__((address_space(3))) void*)(&AhS[(wave * 32 + hh * 16) * 32]), \
        16, 0, 0);                                                              \
    __builtin_amdgcn_global_load_lds(                                           \
        (const __attribute__((address_space(1))) void*)(Al_g + goff),           \
        (__attribute__((address_space(3))) void*)(&AlS[(wave * 32 + hh * 16) * 32]), \
        16, 0, 0);                                                              \
  }

#define LOAD_A_REGS(k0)                                                         \
  pa0 = *(const float4*)(aptr + (k0) + 0);                                      \
  pa1 = *(const float4*)(aptr + (k0) + 4);                                      \
  pa2 = *(const float4*)(aptr + (k0) + 8);                                      \
  pa3 = *(const float4*)(aptr + (k0) + 12);

#define CONVERT_WRITE_A()                                                       \
  {                                                                             \
    int4 H0 = make_int4(pack_hi(pa0.x, pa0.y), pack_hi(pa0.z, pa0.w),           \
                        pack_hi(pa1.x, pa1.y), pack_hi(pa1.z, pa1.w));          \
    int4 H1 = make_int4(pack_hi(pa2.x, pa2.y), pack_hi(pa2.z, pa2.w),           \
                        pack_hi(pa3.x, pa3.y), pack_hi(pa3.z, pa3.w));          \
    int4 L0 = make_int4(pack_lo(pa0.x, pa0.y), pack_lo(pa0.z, pa0.w),           \
                        pack_lo(pa1.x, pa1.y), pack_lo(pa1.z, pa1.w));          \
    int4 L1 = make_int4(pack_lo(pa2.x, pa2.y), pack_lo(pa2.z, pa2.w),           \
                        pack_lo(pa3.x, pa3.y), pack_lo(pa3.z, pa3.w));          \
    *(int4*)&AhS[arow * 32 + ((au0 + 0) ^ akey) * 8] = H0;                      \
    *(int4*)&AhS[arow * 32 + ((au0 + 1) ^ akey) * 8] = H1;                      \
    *(int4*)&AlS[arow * 32 + ((au0 + 0) ^ akey) * 8] = L0;                      \
    *(int4*)&AlS[arow * 32 + ((au0 + 1) ^ akey) * 8] = L1;                      \
  }

  if (AF32) { LOAD_A_REGS(0); }

  for (int kt = 0; kt < NT; ++kt) {
    // ---- stage tile kt into LDS ----
    if (AF32) CONVERT_WRITE_A()
    else      STAGE_A_PRE(kt * 32);
    STAGE_B(kt * 32);
    __syncthreads();
    // ---- next-tile A loads fly under the MFMA block ----
    if (AF32 && kt + 1 < NT) { LOAD_A_REGS((kt + 1) * 32); }
    // ---- fragments + 2-product MFMA ----
    short8 ah[4], al[4];
    #pragma unroll
    for (int mi = 0; mi < 4; ++mi) {
      const int r = wm * 64 + mi * 16 + l15;
      const int aidx = r * 32 + (lg ^ ((r >> 1) & 3)) * 8;
      ah[mi] = *reinterpret_cast<const short8*>(&AhS[aidx]);
      al[mi] = *reinterpret_cast<const short8*>(&AlS[aidx]);
    }
    #pragma unroll
    for (int ni = 0; ni < 4; ++ni) {
      const int c = wn * 64 + ni * 16 + l15;
      const int bidx = c * 32 + (lg ^ ((c >> 1) & 3)) * 8;
      const short8 bh = *reinterpret_cast<const short8*>(&BhS[bidx]);
      #pragma unroll
      for (int mi = 0; mi < 4; ++mi) {
        acc[mi][ni] = __builtin_amdgcn_mfma_f32_16x16x32_bf16(ah[mi], bh, acc[mi][ni], 0, 0, 0);
        acc[mi][ni] = __builtin_amdgcn_mfma_f32_16x16x32_bf16(al[mi], bh, acc[mi][ni], 0, 0, 0);
      }
    }
    __syncthreads();                           // MFMA reads done before overwrite
  }
#undef STAGE_B
#undef STAGE_A_PRE
#undef LOAD_A_REGS
#undef CONVERT_WRITE_A

  // ---- epilogue: C/D map col=lane&15, row=(lane>>4)*4+r ----
  const bool qk_block = (EPI == 0) && (ycol < 8);
  float csum[4] = {};
  #pragma unroll
  for (int mi = 0; mi < 4; ++mi) {
    #pragma unroll
    for (int ni = 0; ni < 4; ++ni) {
      const int col = col0 + wn * 64 + ni * 16 + l15;
      #pragma unroll
      for (int r = 0; r < 4; ++r) {
        const int m = row0 + wm * 64 + mi * 16 + lg * 4 + r;
        const float val = acc[mi][ni][r];
        if (EPI == 0) {
          const int which = col >> 9;
          const int c2 = col & 511;
          const int h = c2 >> 6, d = c2 & 63;
          const int bb = m >> 13, n = m & 8191;
          const size_t idx = (((size_t)(bb * cH + h)) * cN + n) * cD + d;
          if (which < 2) {
            const float sv = 1.f / (1.f + __expf(-val));
            if (which == 0) o0[idx] = sv; else o1[idx] = sv;
            csum[ni] += sv;
          } else {
            o2[idx] = val * 0.125f;
          }
        } else {
          o0[(size_t)m * cC + col] = val + bias[col];
        }
      }
    }
  }
  if (qk_block) {
    #pragma unroll
    for (int ni = 0; ni < 4; ++ni)
      atomicAdd(&colsum[wn * 64 + ni * 16 + l15], csum[ni]);
    __syncthreads();
    if (t < 128) {
      const int col = col0 + t;
      const int c2 = col & 511;
      const int h = c2 >> 6, d = c2 & 63;
      const int bb = row0 >> 13;
      float* tgt = (col < 512) ? qsum : ksum;
      atomicAdd(&tgt[(bb * cH + h) * cD + d], colsum[t]);
    }
  }
}

// ---------------- K34: si, so; accumulate Sq, Sk (4 rows/wave/iter, float4) ----------------
__global__ __launch_bounds__(256) void k34_flow(const float* __restrict__ q,
      const float* __restrict__ k, const float* __restrict__ qsum,
      const float* __restrict__ ksum, float* __restrict__ si,
      float* __restrict__ Sq, float* __restrict__ Sk) {
  const int bh = blockIdx.x;
  const int n0 = blockIdx.y * 256;
  const int t = threadIdx.x;
  const int wave = t >> 6, lane = t & 63;
  const int g = lane >> 4, j = lane & 15;
  const float* qb = q + (size_t)bh * cN * cD;
  const float* kb = k + (size_t)bh * cN * cD;
  const float4 ks4 = *(const float4*)&ksum[bh * 64 + j * 4];
  const float4 qs4 = *(const float4*)&qsum[bh * 64 + j * 4];
  const float ksd[4] = {ks4.x + kEPS, ks4.y + kEPS, ks4.z + kEPS, ks4.w + kEPS};
  const float qsd[4] = {qs4.x + kEPS, qs4.y + kEPS, qs4.z + kEPS, qs4.w + kEPS};
  float aSq[4] = {}, aSk[4] = {};
  for (int i = 0; i < 16; ++i) {
    const int n = n0 + wave * 64 + i * 4 + g;
    const float4 q4 = *(const float4*)&qb[(size_t)n * cD + j * 4];
    const float4 k4 = *(const float4*)&kb[(size_t)n * cD + j * 4];
    const float qa[4] = {q4.x, q4.y, q4.z, q4.w};
    const float ka[4] = {k4.x, k4.y, k4.z, k4.w};
    float t1 = 0.f, t2 = 0.f;
    #pragma unroll
    for (int c = 0; c < 4; ++c) {
      t1 = fmaf(qa[c] + kEPS, ksd[c], t1);
      t2 = fmaf(ka[c] + kEPS, qsd[c], t2);
    }
    #pragma unroll
    for (int off = 1; off < 16; off <<= 1) {
      t1 += __shfl_xor(t1, off);
      t2 += __shfl_xor(t2, off);
    }
    const float si_n = 1.f / (t1 + kEPS);
    const float so_n = 1.f / (t2 + kEPS);
    if (j == 0) si[(size_t)bh * cN + n] = si_n;
    #pragma unroll
    for (int c = 0; c < 4; ++c) {
      aSq[c] = fmaf(qa[c], si_n, aSq[c]);
      aSk[c] = fmaf(ka[c], so_n, aSk[c]);
    }
  }
  #pragma unroll
  for (int c = 0; c < 4; ++c) {
    aSq[c] += __shfl_xor(aSq[c], 16); aSq[c] += __shfl_xor(aSq[c], 32);
    aSk[c] += __shfl_xor(aSk[c], 16); aSk[c] += __shfl_xor(aSk[c], 32);
  }
  __shared__ float sAq[4][64], sAk[4][64];
  if (g == 0) {
    #pragma unroll
    for (int c = 0; c < 4; ++c) { sAq[wave][j * 4 + c] = aSq[c]; sAk[wave][j * 4 + c] = aSk[c]; }
  }
  __syncthreads();
  if (t < 64) {
    atomicAdd(&Sq[bh * 64 + t], sAq[0][t] + sAq[1][t] + sAq[2][t] + sAq[3][t]);
    atomicAdd(&Sk[bh * 64 + t], sAk[0][t] + sAk[1][t] + sAk[2][t] + sAk[3][t]);
  }
}

// ---------------- K45: split-K kv partials (NO atomics), ev inline ----------------
__global__ __launch_bounds__(256) void k45_kv(const float* __restrict__ kk_,
      const float* __restrict__ vv, const float* __restrict__ Sq,
      float* __restrict__ kvpart, float* __restrict__ zpart) {
  const int bh = blockIdx.x;
  const int y = blockIdx.y;                       // KV_SPLIT slices
  constexpr int ROWS = cN / KV_SPLIT;             // 256
  const int n0 = y * ROWS;
  const int t = threadIdx.x;
  const int d = t & 63, eb = t >> 6;
  const int g = t >> 4, j = t & 15;               // 16 ev-groups of 16 lanes
  const int sr = t >> 4, sc = (t & 15) * 4;       // stage mapping
  const float* kb = kk_ + (size_t)bh * cN * cD;
  const float* vb = vv + (size_t)bh * cN * cD;
  const float4 sq4 = *(const float4*)&Sq[bh * 64 + j * 4];
  const float SqE[4] = {sq4.x + kEPS, sq4.y + kEPS, sq4.z + kEPS, sq4.w + kEPS};
  __shared__ float ks[32][64];
  __shared__ float vs[32][64];
  __shared__ float evs[32];
  __shared__ float zl[16];
  float acc[16] = {};
  float zacc = 0.f;
  float4 pk0 = *(const float4*)&kb[(size_t)(n0 + sr) * cD + sc];
  float4 pk1 = *(const float4*)&kb[(size_t)(n0 + 16 + sr) * cD + sc];
  float4 pv0 = *(const float4*)&vb[(size_t)(n0 + sr) * cD + sc];
  float4 pv1 = *(const float4*)&vb[(size_t)(n0 + 16 + sr) * cD + sc];
  for (int c0 = 0; c0 < ROWS; c0 += 32) {
    __syncthreads();
    *(float4*)&ks[sr][sc]      = pk0;
    *(float4*)&ks[sr + 16][sc] = pk1;
    *(float4*)&vs[sr][sc]      = pv0;
    *(float4*)&vs[sr + 16][sc] = pv1;
    __syncthreads();
    if (c0 + 32 < ROWS) {
      pk0 = *(const float4*)&kb[(size_t)(n0 + c0 + 32 + sr) * cD + sc];
      pk1 = *(const float4*)&kb[(size_t)(n0 + c0 + 48 + sr) * cD + sc];
      pv0 = *(const float4*)&vb[(size_t)(n0 + c0 + 32 + sr) * cD + sc];
      pv1 = *(const float4*)&vb[(size_t)(n0 + c0 + 48 + sr) * cD + sc];
    }
    #pragma unroll
    for (int rr = 0; rr < 2; ++rr) {
      const int r = g * 2 + rr;
      const float4 kk4 = *(const float4*)&ks[r][j * 4];
      float tt = 0.f;
      tt = fmaf(kk4.x + kEPS, SqE[0], tt);
      tt = fmaf(kk4.y + kEPS, SqE[1], tt);
      tt = fmaf(kk4.z + kEPS, SqE[2], tt);
      tt = fmaf(kk4.w + kEPS, SqE[3], tt);
      #pragma unroll
      for (int off = 1; off < 16; off <<= 1) tt += __shfl_xor(tt, off);
      if (j == 0) {
        const float cs = fminf(fmaxf(tt + kEPS, -1.f), 1.f);
        const float e = __expf(cs);
        evs[r] = e;
        zacc += e;
      }
    }
    __syncthreads();
    #pragma unroll
    for (int r = 0; r < 32; ++r) {
      const float kd = ks[r][d] * evs[r];
      #pragma unroll
      for (int j2 = 0; j2 < 16; ++j2)
        acc[j2] = fmaf(kd, vs[r][eb * 16 + j2], acc[j2]);
    }
  }
  if (j == 0) zl[g] = zacc;
  __syncthreads();
  if (t == 0) {
    float z = 0.f;
    #pragma unroll
    for (int i = 0; i < 16; ++i) z += zl[i];
    zpart[y * cBH + bh] = z;
  }
  float* kvb = kvpart + ((size_t)y * cBH + bh) * 4096 + d * 64 + eb * 16;
  #pragma unroll
  for (int j2 = 0; j2 < 16; ++j2) kvb[j2] = acc[j2];
}

// ---------------- K5R: fold split-K partials -> kvm, Zb (deterministic) ----------------
__global__ __launch_bounds__(256) void k5r_reduce(const float* __restrict__ kvpart,
      const float* __restrict__ zpart, float* __restrict__ kvm, float* __restrict__ Zb) {
  const int bh = blockIdx.x;
  const int yq = blockIdx.y;                      // 4 chunks of 1024
  const int t = threadIdx.x;
  for (int i = yq * 1024 + t; i < (yq + 1) * 1024; i += 256) {
    float s = 0.f;
    #pragma unroll
    for (int yy = 0; yy < KV_SPLIT; ++yy)
      s += kvpart[((size_t)yy * cBH + bh) * 4096 + i];
    kvm[(size_t)bh * 4096 + i] = s;
  }
  if (yq == 0 && t == 0) {
    float z = 0.f;
    #pragma unroll
    for (int yy = 0; yy < KV_SPLIT; ++yy) z += zpart[yy * cBH + bh];
    Zb[bh] = z;
  }
}

// ---------------- K6b: xu = (q @ kv*(N/Z)) * si * sa -> split bf16 [M][512] ----------------
__global__ __launch_bounds__(256) void k6b_xu(const float* __restrict__ q,
      const float* __restrict__ kvmat, const float* __restrict__ si,
      const float* __restrict__ Sk, const float* __restrict__ Zb,
      ushort* __restrict__ xh, ushort* __restrict__ xl) {
  const int bh = blockIdx.x;
  const int b = bh >> 3, head = bh & 7;
  const int n0 = blockIdx.y * 64;
  const int lane = threadIdx.x & 63;
  const int wave = threadIdx.x >> 6;
  __shared__ float kvs[64][64];
  const float zs = (float)cN / Zb[bh];
  for (int i = threadIdx.x; i < 4096; i += 256)
    kvs[i >> 6][i & 63] = kvmat[(size_t)bh * 4096 + i] * zs;
  const float SkE = Sk[bh * 64 + lane] + kEPS;
  __syncthreads();
  const float* qb = q + (size_t)bh * cN * cD;
  for (int i = 0; i < 16; ++i) {
    const int n = n0 + wave * 16 + i;
    const float qd = qb[(size_t)n * cD + lane];
    float t2 = (qd + kEPS) * SkE;
    #pragma unroll
    for (int off = 1; off < 64; off <<= 1) t2 += __shfl_xor(t2, off);
    const float sa_n = 1.f / (1.f + __expf(-(t2 + kEPS)));
    float a0 = 0.f, a1 = 0.f, a2 = 0.f, a3 = 0.f;
    #pragma unroll
    for (int dd = 0; dd < 64; dd += 4) {
      a0 = fmaf(__shfl(qd, dd),     kvs[dd][lane],     a0);
      a1 = fmaf(__shfl(qd, dd + 1), kvs[dd + 1][lane], a1);
      a2 = fmaf(__shfl(qd, dd + 2), kvs[dd + 2][lane], a2);
      a3 = fmaf(__shfl(qd, dd + 3), kvs[dd + 3][lane], a3);
    }
    const float s = si[(size_t)bh * cN + n] * sa_n;
    const float val = ((a0 + a1) + (a2 + a3)) * s;
    ushort hbits, lbits;
    split2(val, hbits, lbits);
    const size_t m = (size_t)b * cN + n;
    xh[m * cC + head * 64 + lane] = hbits;
    xl[m * cC + head * 64 + lane] = lbits;
  }
}

extern "C" void kernel_launch(void* const* d_in, const int* in_sizes, int n_in,
                              void* d_out, int out_size, void* d_ws, size_t ws_size,
                              hipStream_t stream) {
  (void)in_sizes; (void)n_in; (void)out_size;
  const float* x     = (const float*)d_in[0];
  const float* Wqkv  = (const float*)d_in[1];
  const float* Wproj = (const float*)d_in[2];
  const float* bproj = (const float*)d_in[3];
  float* out = (float*)d_out;
  float* ws  = (float*)d_ws;

  const size_t SLAB = (size_t)cBH * cN * cD;       // 16,777,216 floats (64 MB)
  const size_t OFF_Q   = 0;
  const size_t OFF_K   = SLAB;
  const size_t OFF_V   = 2 * SLAB;                 // xu hi/lo alias v (dead after K45)
  const size_t OFF_ACC = 3 * SLAB;
  const size_t ACC_FLOATS = 2048 * 4 + 32 + (size_t)cBH * cD * cD;  // 139,296
  const size_t OFF_R   = OFF_ACC + ACC_FLOATS;     // time-shared region
  const size_t R_FLOATS = (size_t)3 * cHD * cC / 2;  // 393,216 floats (wq single-bf16)
  const size_t TOTAL   = OFF_R + R_FLOATS;         // < round-8 footprint (proven fit)
  if (ws_size < TOTAL * sizeof(float)) return;

  float* q    = ws + OFF_Q;
  float* k    = ws + OFF_K;
  float* v    = ws + OFF_V;
  float* ksum = ws + OFF_ACC;
  float* qsum = ksum + 2048;
  float* Sk   = ksum + 4096;
  float* Sq   = ksum + 6144;
  float* Zb   = ksum + 8192;
  float* kvm  = ksum + 8224;

  // region R timeline (393,216 floats):
  //   [0 .. 393216)        wq bf16      alive: round_w(wq) -> gemm0
  //   [0 .. 262144)        si           alive: k34 -> k6b        (after gemm0)
  //   [262144 .. 393216)   wp bf16      alive: round_w(wp) -> gemm1 (after gemm0)
  ushort* wq  = (ushort*)(ws + OFF_R);
  float*  si  = ws + OFF_R;
  ushort* wp  = (ushort*)(ws + OFF_R + (size_t)cBH * cN);   // +262144 floats
  // xu bf16 hi/lo overlay the v slab (v dead after K45)
  ushort* xh = (ushort*)(ws + OFF_V);
  ushort* xl = xh + (size_t)cM * cHD;

  // k45 split-K partials in d_out are legal: their lifetime (k45 -> k5r) ends
  // before gemm1 (the d_out writer) starts. gemm1 reads NOTHING from d_out.
  float* kvpart = out;                                   // 16 MB
  float* zpart  = out + (size_t)KV_SPLIT * cBH * 4096;   // 1024 floats

  hipMemsetAsync(ksum, 0, ACC_FLOATS * sizeof(float), stream);

  round_w<<<(3 * cHD * cC / 4 + 255) / 256, 256, 0, stream>>>(Wqkv, wq, 3 * cHD * cC / 4);
  gemm_mfma<0, 12><<<dim3(cM / 128, (3 * cHD) / 128), 256, 0, stream>>>(
      x, nullptr, nullptr, wq, nullptr, q, k, v, qsum, ksum);
  round_w<<<(cC * cHD / 4 + 255) / 256, 256, 0, stream>>>(Wproj, wp, cC * cHD / 4);
  k34_flow<<<dim3(cBH, cN / 256), 256, 0, stream>>>(q, k, qsum, ksum, si, Sq, Sk);
  k45_kv<<<dim3(cBH, KV_SPLIT), 256, 0, stream>>>(k, v, Sq, kvpart, zpart);
  k5r_reduce<<<dim3(cBH, 4), 256, 0, stream>>>(kvpart, zpart, kvm, Zb);
  k6b_xu<<<dim3(cBH, cN / 64), 256, 0, stream>>>(q, kvm, si, Sk, Zb, xh, xl);
  gemm_mfma<1, 4><<<dim3(cM / 128, cHD / 128), 256, 0, stream>>>(
      nullptr, xh, xl, wp, bproj, out, nullptr, nullptr, nullptr, nullptr);
}

// Round 10
// 339.152 us; speedup vs baseline: 1.7893x; 1.4561x over previous
//
#include <hip/hip_runtime.h>
#include <hip/hip_bf16.h>

typedef __attribute__((ext_vector_type(8))) short short8;
typedef __attribute__((ext_vector_type(4))) float f32x4;

constexpr int cB = 4, cN = 8192, cC = 512, cH = 8, cD = 64;
constexpr int cM = cB * cN;        // 32768 tokens
constexpr int cHD = cH * cD;       // 512
constexpr int cBH = cB * cH;       // 32
constexpr float kEPS = 1e-6f;
constexpr int KV_SPLIT = 32;       // k45 split-K slices

// ---- split f32 -> (bf16 hi by truncation, bf16 lo of remainder) — exact-A path ----
__device__ __forceinline__ void split2(float f, ushort& h, ushort& l) {
  unsigned u = __float_as_uint(f);
  h = (ushort)(u >> 16);
  float fl = f - __uint_as_float(u & 0xffff0000u);
  l = (ushort)(__float_as_uint(fl) >> 16);
}
__device__ __forceinline__ int pack_hi(float a, float b) {
  return (int)((__float_as_uint(a) >> 16) | (__float_as_uint(b) & 0xffff0000u));
}
__device__ __forceinline__ int pack_lo(float a, float b) {
  float la = a - __uint_as_float(__float_as_uint(a) & 0xffff0000u);
  float lb = b - __uint_as_float(__float_as_uint(b) & 0xffff0000u);
  return (int)((__float_as_uint(la) >> 16) | (__float_as_uint(lb) & 0xffff0000u));
}
// ---- RNE f32 -> bf16 (unbiased; for single-bf16 weight operands) ----
__device__ __forceinline__ ushort rne_bf16(float f) {
  unsigned u = __float_as_uint(f);
  u += 0x7fffu + ((u >> 16) & 1u);
  return (ushort)(u >> 16);
}

// ---------------- weight rounder: f32 -> single bf16 (RNE) ----------------
__global__ __launch_bounds__(256) void round_w(const float* __restrict__ src,
    ushort* __restrict__ w, int n4) {
  int i = blockIdx.x * 256 + threadIdx.x;
  if (i >= n4) return;
  float4 v = reinterpret_cast<const float4*>(src)[i];
  ushort4 h;
  h.x = rne_bf16(v.x); h.y = rne_bf16(v.y);
  h.z = rne_bf16(v.z); h.w = rne_bf16(v.w);
  reinterpret_cast<ushort4*>(w)[i] = h;
}

// ---------------- 2-product MFMA GEMM: C = A[Mx512] @ W[NCx512]^T ----------------
// A exact (bf16 hi+lo), B single bf16 (RNE). acc = Ah*B + Al*B.
// Single-buffer LDS (24 KB), 2 barriers/K-step; A-reg prefetch under MFMA.
// XOR-unit swizzle (0 conflicts, r8) + bijective XCD swizzle (FETCH halved, r8).
// EPI=0: A f32 reg-staged+converted; epilogue qkv scatter + fused qsum/ksum.
// EPI=1: A pre-split bf16 via global_load_lds; epilogue out + bias.
//        bstride: per-b B-matrix offset (kvW is per-batch); 0 = shared weights.
// NOTE (r7 lesson): gemm1 reads NOTHING from d_out (intra-kernel race).
template<int EPI, int NY>
__global__ __launch_bounds__(256) void gemm_mfma(
    const float* __restrict__ A,
    const ushort* __restrict__ Ah_g, const ushort* __restrict__ Al_g,
    const ushort* __restrict__ Wb, int bstride,
    const float* __restrict__ bias,
    float* __restrict__ o0, float* __restrict__ o1, float* __restrict__ o2,
    float* __restrict__ qsum, float* __restrict__ ksum) {
  constexpr bool AF32 = (EPI == 0);
  constexpr int NT = cC / 32;                   // 16 K-steps of BK=32
  __shared__ ushort AhS[128 * 32], AlS[128 * 32];
  __shared__ ushort BhS[128 * 32];
  __shared__ float colsum[128];
  const int t = threadIdx.x;
  const int wave = t >> 6, lane = t & 63;
  const int wm = wave >> 1, wn = wave & 1;      // 2x2 waves of 64x64
  const int l15 = lane & 15, lg = lane >> 4;

  // ---- XCD-chunked bijective swizzle (nwg % 8 == 0 for both launches) ----
  const int raw = blockIdx.y * gridDim.x + blockIdx.x;
  const int q8 = (int)(gridDim.x * NY) >> 3;
  const int wg2 = (raw & 7) * q8 + (raw >> 3);
  const int rowchunk = wg2 / NY, ycol = wg2 - rowchunk * NY;
  const int row0 = rowchunk * 128, col0 = ycol * 128;
  const size_t wofs = (size_t)(row0 >> 13) * (size_t)bstride;  // per-b B offset

  if (EPI == 0 && t < 128) colsum[t] = 0.f;     // ordered by loop barriers

  f32x4 acc[4][4] = {};

  const int srow = lane >> 2, sunit = lane & 3; // bf16 gld_lds stage mapping
  const int arow = t >> 1, akh = (t & 1) * 16;  // A f32 reg-stage mapping
  const float* aptr = AF32 ? (A + (size_t)(row0 + arow) * cC + akh) : nullptr;
  const int akey = (arow >> 1) & 3;
  const int au0 = (t & 1) * 2;

  float4 pa0, pa1, pa2, pa3;                    // A prefetch regs (EPI=0)

#define STAGE_B(k0)                                                             \
  _Pragma("unroll")                                                             \
  for (int hh = 0; hh < 2; ++hh) {                                              \
    const int br = wave * 32 + hh * 16 + srow;                                  \
    const int sw = sunit ^ ((br >> 1) & 3);                                     \
    const size_t goff = wofs + (size_t)(col0 + br) * cC + (k0) + sw * 8;        \
    __builtin_amdgcn_global_load_lds(                                           \
        (const __attribute__((address_space(1))) void*)(Wb + goff),             \
        (__attribute__((address_space(3))) void*)(&BhS[(wave * 32 + hh * 16) * 32]), \
        16, 0, 0);                                                              \
  }

#define STAGE_A_PRE(k0)                                                         \
  _Pragma("unroll")                                                             \
  for (int hh = 0; hh < 2; ++hh) {                                              \
    const int ar = wave * 32 + hh * 16 + srow;                                  \
    const int sw = sunit ^ ((ar >> 1) & 3);                                     \
    const size_t goff = (size_t)(row0 + ar) * cC + (k0) + sw * 8;               \
    __builtin_amdgcn_global_load_lds(                                           \
        (const __attribute__((address_space(1))) void*)(Ah_g + goff),           \
        (__attribute__((address_space(3))) void*)(&AhS[(wave * 32 + hh * 16) * 32]), \
        16, 0, 0);                                                              \
    __builtin_amdgcn_global_load_lds(                                           \
        (const __attribute__((address_space(1))) void*)(Al_g + goff),           \
        (__attribute__((address_space(3))) void*)(&AlS[(wave * 32 + hh * 16) * 32]), \
        16, 0, 0);                                                              \
  }

#define LOAD_A_REGS(k0)                                                         \
  pa0 = *(const float4*)(aptr + (k0) + 0);                                      \
  pa1 = *(const float4*)(aptr + (k0) + 4);                                      \
  pa2 = *(const float4*)(aptr + (k0) + 8);                                      \
  pa3 = *(const float4*)(aptr + (k0) + 12);

#define CONVERT_WRITE_A()                                                       \
  {                                                                             \
    int4 H0 = make_int4(pack_hi(pa0.x, pa0.y), pack_hi(pa0.z, pa0.w),           \
                        pack_hi(pa1.x, pa1.y), pack_hi(pa1.z, pa1.w));          \
    int4 H1 = make_int4(pack_hi(pa2.x, pa2.y), pack_hi(pa2.z, pa2.w),           \
                        pack_hi(pa3.x, pa3.y), pack_hi(pa3.z, pa3.w));          \
    int4 L0 = make_int4(pack_lo(pa0.x, pa0.y), pack_lo(pa0.z, pa0.w),           \
                        pack_lo(pa1.x, pa1.y), pack_lo(pa1.z, pa1.w));          \
    int4 L1 = make_int4(pack_lo(pa2.x, pa2.y), pack_lo(pa2.z, pa2.w),           \
                        pack_lo(pa3.x, pa3.y), pack_lo(pa3.z, pa3.w));          \
    *(int4*)&AhS[arow * 32 + ((au0 + 0) ^ akey) * 8] = H0;                      \
    *(int4*)&AhS[arow * 32 + ((au0 + 1) ^ akey) * 8] = H1;                      \
    *(int4*)&AlS[arow * 32 + ((au0 + 0) ^ akey) * 8] = L0;                      \
    *(int4*)&AlS[arow * 32 + ((au0 + 1) ^ akey) * 8] = L1;                      \
  }

  if (AF32) { LOAD_A_REGS(0); }

  for (int kt = 0; kt < NT; ++kt) {
    // ---- stage tile kt into LDS ----
    if (AF32) CONVERT_WRITE_A()
    else      STAGE_A_PRE(kt * 32);
    STAGE_B(kt * 32);
    __syncthreads();
    // ---- next-tile A loads fly under the MFMA block ----
    if (AF32 && kt + 1 < NT) { LOAD_A_REGS((kt + 1) * 32); }
    // ---- fragments + 2-product MFMA ----
    short8 ah[4], al[4];
    #pragma unroll
    for (int mi = 0; mi < 4; ++mi) {
      const int r = wm * 64 + mi * 16 + l15;
      const int aidx = r * 32 + (lg ^ ((r >> 1) & 3)) * 8;
      ah[mi] = *reinterpret_cast<const short8*>(&AhS[aidx]);
      al[mi] = *reinterpret_cast<const short8*>(&AlS[aidx]);
    }
    #pragma unroll
    for (int ni = 0; ni < 4; ++ni) {
      const int c = wn * 64 + ni * 16 + l15;
      const int bidx = c * 32 + (lg ^ ((c >> 1) & 3)) * 8;
      const short8 bh = *reinterpret_cast<const short8*>(&BhS[bidx]);
      #pragma unroll
      for (int mi = 0; mi < 4; ++mi) {
        acc[mi][ni] = __builtin_amdgcn_mfma_f32_16x16x32_bf16(ah[mi], bh, acc[mi][ni], 0, 0, 0);
        acc[mi][ni] = __builtin_amdgcn_mfma_f32_16x16x32_bf16(al[mi], bh, acc[mi][ni], 0, 0, 0);
      }
    }
    __syncthreads();                           // MFMA reads done before overwrite
  }
#undef STAGE_B
#undef STAGE_A_PRE
#undef LOAD_A_REGS
#undef CONVERT_WRITE_A

  // ---- epilogue: C/D map col=lane&15, row=(lane>>4)*4+r ----
  const bool qk_block = (EPI == 0) && (ycol < 8);
  float csum[4] = {};
  #pragma unroll
  for (int mi = 0; mi < 4; ++mi) {
    #pragma unroll
    for (int ni = 0; ni < 4; ++ni) {
      const int col = col0 + wn * 64 + ni * 16 + l15;
      #pragma unroll
      for (int r = 0; r < 4; ++r) {
        const int m = row0 + wm * 64 + mi * 16 + lg * 4 + r;
        const float val = acc[mi][ni][r];
        if (EPI == 0) {
          const int which = col >> 9;
          const int c2 = col & 511;
          const int h = c2 >> 6, d = c2 & 63;
          const int bb = m >> 13, n = m & 8191;
          const size_t idx = (((size_t)(bb * cH + h)) * cN + n) * cD + d;
          if (which < 2) {
            const float sv = 1.f / (1.f + __expf(-val));
            if (which == 0) o0[idx] = sv; else o1[idx] = sv;
            csum[ni] += sv;
          } else {
            o2[idx] = val * 0.125f;
          }
        } else {
          o0[(size_t)m * cC + col] = val + bias[col];
        }
      }
    }
  }
  if (qk_block) {
    #pragma unroll
    for (int ni = 0; ni < 4; ++ni)
      atomicAdd(&colsum[wn * 64 + ni * 16 + l15], csum[ni]);
    __syncthreads();
    if (t < 128) {
      const int col = col0 + t;
      const int c2 = col & 511;
      const int h = c2 >> 6, d = c2 & 63;
      const int bb = row0 >> 13;
      float* tgt = (col < 512) ? qsum : ksum;
      atomicAdd(&tgt[(bb * cH + h) * cD + d], colsum[t]);
    }
  }
}

// ---------------- K34: si, so; accumulate Sq, Sk (4 rows/wave/iter, float4) ----------------
__global__ __launch_bounds__(256) void k34_flow(const float* __restrict__ q,
      const float* __restrict__ k, const float* __restrict__ qsum,
      const float* __restrict__ ksum, float* __restrict__ si,
      float* __restrict__ Sq, float* __restrict__ Sk) {
  const int bh = blockIdx.x;
  const int n0 = blockIdx.y * 256;
  const int t = threadIdx.x;
  const int wave = t >> 6, lane = t & 63;
  const int g = lane >> 4, j = lane & 15;
  const float* qb = q + (size_t)bh * cN * cD;
  const float* kb = k + (size_t)bh * cN * cD;
  const float4 ks4 = *(const float4*)&ksum[bh * 64 + j * 4];
  const float4 qs4 = *(const float4*)&qsum[bh * 64 + j * 4];
  const float ksd[4] = {ks4.x + kEPS, ks4.y + kEPS, ks4.z + kEPS, ks4.w + kEPS};
  const float qsd[4] = {qs4.x + kEPS, qs4.y + kEPS, qs4.z + kEPS, qs4.w + kEPS};
  float aSq[4] = {}, aSk[4] = {};
  for (int i = 0; i < 16; ++i) {
    const int n = n0 + wave * 64 + i * 4 + g;
    const float4 q4 = *(const float4*)&qb[(size_t)n * cD + j * 4];
    const float4 k4 = *(const float4*)&kb[(size_t)n * cD + j * 4];
    const float qa[4] = {q4.x, q4.y, q4.z, q4.w};
    const float ka[4] = {k4.x, k4.y, k4.z, k4.w};
    float t1 = 0.f, t2 = 0.f;
    #pragma unroll
    for (int c = 0; c < 4; ++c) {
      t1 = fmaf(qa[c] + kEPS, ksd[c], t1);
      t2 = fmaf(ka[c] + kEPS, qsd[c], t2);
    }
    #pragma unroll
    for (int off = 1; off < 16; off <<= 1) {
      t1 += __shfl_xor(t1, off);
      t2 += __shfl_xor(t2, off);
    }
    const float si_n = 1.f / (t1 + kEPS);
    const float so_n = 1.f / (t2 + kEPS);
    if (j == 0) si[(size_t)bh * cN + n] = si_n;
    #pragma unroll
    for (int c = 0; c < 4; ++c) {
      aSq[c] = fmaf(qa[c], si_n, aSq[c]);
      aSk[c] = fmaf(ka[c], so_n, aSk[c]);
    }
  }
  #pragma unroll
  for (int c = 0; c < 4; ++c) {
    aSq[c] += __shfl_xor(aSq[c], 16); aSq[c] += __shfl_xor(aSq[c], 32);
    aSk[c] += __shfl_xor(aSk[c], 16); aSk[c] += __shfl_xor(aSk[c], 32);
  }
  __shared__ float sAq[4][64], sAk[4][64];
  if (g == 0) {
    #pragma unroll
    for (int c = 0; c < 4; ++c) { sAq[wave][j * 4 + c] = aSq[c]; sAk[wave][j * 4 + c] = aSk[c]; }
  }
  __syncthreads();
  if (t < 64) {
    atomicAdd(&Sq[bh * 64 + t], sAq[0][t] + sAq[1][t] + sAq[2][t] + sAq[3][t]);
    atomicAdd(&Sk[bh * 64 + t], sAk[0][t] + sAk[1][t] + sAk[2][t] + sAk[3][t]);
  }
}

// ---------------- K45: split-K kv partials (NO atomics), ev inline ----------------
__global__ __launch_bounds__(256) void k45_kv(const float* __restrict__ kk_,
      const float* __restrict__ vv, const float* __restrict__ Sq,
      float* __restrict__ kvpart, float* __restrict__ zpart) {
  const int bh = blockIdx.x;
  const int y = blockIdx.y;                       // KV_SPLIT slices
  constexpr int ROWS = cN / KV_SPLIT;             // 256
  const int n0 = y * ROWS;
  const int t = threadIdx.x;
  const int d = t & 63, eb = t >> 6;
  const int g = t >> 4, j = t & 15;               // 16 ev-groups of 16 lanes
  const int sr = t >> 4, sc = (t & 15) * 4;       // stage mapping
  const float* kb = kk_ + (size_t)bh * cN * cD;
  const float* vb = vv + (size_t)bh * cN * cD;
  const float4 sq4 = *(const float4*)&Sq[bh * 64 + j * 4];
  const float SqE[4] = {sq4.x + kEPS, sq4.y + kEPS, sq4.z + kEPS, sq4.w + kEPS};
  __shared__ float ks[32][64];
  __shared__ float vs[32][64];
  __shared__ float evs[32];
  __shared__ float zl[16];
  float acc[16] = {};
  float zacc = 0.f;
  float4 pk0 = *(const float4*)&kb[(size_t)(n0 + sr) * cD + sc];
  float4 pk1 = *(const float4*)&kb[(size_t)(n0 + 16 + sr) * cD + sc];
  float4 pv0 = *(const float4*)&vb[(size_t)(n0 + sr) * cD + sc];
  float4 pv1 = *(const float4*)&vb[(size_t)(n0 + 16 + sr) * cD + sc];
  for (int c0 = 0; c0 < ROWS; c0 += 32) {
    __syncthreads();
    *(float4*)&ks[sr][sc]      = pk0;
    *(float4*)&ks[sr + 16][sc] = pk1;
    *(float4*)&vs[sr][sc]      = pv0;
    *(float4*)&vs[sr + 16][sc] = pv1;
    __syncthreads();
    if (c0 + 32 < ROWS) {
      pk0 = *(const float4*)&kb[(size_t)(n0 + c0 + 32 + sr) * cD + sc];
      pk1 = *(const float4*)&kb[(size_t)(n0 + c0 + 48 + sr) * cD + sc];
      pv0 = *(const float4*)&vb[(size_t)(n0 + c0 + 32 + sr) * cD + sc];
      pv1 = *(const float4*)&vb[(size_t)(n0 + c0 + 48 + sr) * cD + sc];
    }
    #pragma unroll
    for (int rr = 0; rr < 2; ++rr) {
      const int r = g * 2 + rr;
      const float4 kk4 = *(const float4*)&ks[r][j * 4];
      float tt = 0.f;
      tt = fmaf(kk4.x + kEPS, SqE[0], tt);
      tt = fmaf(kk4.y + kEPS, SqE[1], tt);
      tt = fmaf(kk4.z + kEPS, SqE[2], tt);
      tt = fmaf(kk4.w + kEPS, SqE[3], tt);
      #pragma unroll
      for (int off = 1; off < 16; off <<= 1) tt += __shfl_xor(tt, off);
      if (j == 0) {
        const float cs = fminf(fmaxf(tt + kEPS, -1.f), 1.f);
        const float e = __expf(cs);
        evs[r] = e;
        zacc += e;
      }
    }
    __syncthreads();
    #pragma unroll
    for (int r = 0; r < 32; ++r) {
      const float kd = ks[r][d] * evs[r];
      #pragma unroll
      for (int j2 = 0; j2 < 16; ++j2)
        acc[j2] = fmaf(kd, vs[r][eb * 16 + j2], acc[j2]);
    }
  }
  if (j == 0) zl[g] = zacc;
  __syncthreads();
  if (t == 0) {
    float z = 0.f;
    #pragma unroll
    for (int i = 0; i < 16; ++i) z += zl[i];
    zpart[y * cBH + bh] = z;
  }
  float* kvb = kvpart + ((size_t)y * cBH + bh) * 4096 + d * 64 + eb * 16;
  #pragma unroll
  for (int j2 = 0; j2 < 16; ++j2) kvb[j2] = acc[j2];
}

// ---------------- K5R: fold split-K partials -> kvm, Zb (deterministic) ----------------
__global__ __launch_bounds__(256) void k5r_reduce(const float* __restrict__ kvpart,
      const float* __restrict__ zpart, float* __restrict__ kvm, float* __restrict__ Zb) {
  const int bh = blockIdx.x;
  const int yq = blockIdx.y;                      // 4 chunks of 1024
  const int t = threadIdx.x;
  for (int i = yq * 1024 + t; i < (yq + 1) * 1024; i += 256) {
    float s = 0.f;
    #pragma unroll
    for (int yy = 0; yy < KV_SPLIT; ++yy)
      s += kvpart[((size_t)yy * cBH + bh) * 4096 + i];
    kvm[(size_t)bh * 4096 + i] = s;
  }
  if (yq == 0 && t == 0) {
    float z = 0.f;
    #pragma unroll
    for (int yy = 0; yy < KV_SPLIT; ++yy) z += zpart[yy * cBH + bh];
    Zb[bh] = z;
  }
}

// ---------------- KVW: kvw[b][c*512 + h*64+d] = RNE( (N/Z)·(kv_bh @ Wproj_h^T)[d,c] ) ----------------
__global__ __launch_bounds__(256) void kvw_build(const float* __restrict__ kvm,
      const float* __restrict__ Wproj, const float* __restrict__ Zb,
      ushort* __restrict__ kvw) {
  const int bh = blockIdx.x;                     // 32
  const int c0 = blockIdx.y * 128;               // 4 c-chunks
  const int b = bh >> 3, h = bh & 7;
  const int t = threadIdx.x;
  __shared__ float kvs[64][64];
  for (int i = t; i < 4096; i += 256)
    kvs[i >> 6][i & 63] = kvm[(size_t)bh * 4096 + i];
  __syncthreads();
  const float zs = (float)cN / Zb[bh];
  const int cl = t & 127, half = t >> 7;         // c-local, d-half
  const int c = c0 + cl;
  float acc[32] = {};
  for (int ec = 0; ec < 64; ec += 8) {
    float w[8];
    #pragma unroll
    for (int e = 0; e < 8; ++e)
      w[e] = Wproj[(size_t)c * cHD + h * 64 + ec + e];
    #pragma unroll
    for (int d = 0; d < 32; ++d)
      #pragma unroll
      for (int e = 0; e < 8; ++e)
        acc[d] = fmaf(kvs[half * 32 + d][ec + e], w[e], acc[d]);
  }
  ushort* dst = kvw + (size_t)b * cC * cHD + (size_t)c * cC + h * 64 + half * 32;
  #pragma unroll
  for (int d = 0; d < 32; ++d) dst[d] = rne_bf16(acc[d] * zs);
}

// ---------------- K6c: A' = q · si · sa -> exact bf16 hi/lo, [M][512] token-major ----------------
__global__ __launch_bounds__(256) void k6c_scaleq(const float* __restrict__ q,
      const float* __restrict__ si, const float* __restrict__ Sk,
      ushort* __restrict__ xh, ushort* __restrict__ xl) {
  const int bh = blockIdx.x;
  const int b = bh >> 3, head = bh & 7;
  const int n0 = blockIdx.y * 256;
  const int t = threadIdx.x;
  const int wave = t >> 6, lane = t & 63;
  const int g = lane >> 4, j = lane & 15;
  const float* qb = q + (size_t)bh * cN * cD;
  const float4 sk4 = *(const float4*)&Sk[bh * 64 + j * 4];
  const float SkE[4] = {sk4.x + kEPS, sk4.y + kEPS, sk4.z + kEPS, sk4.w + kEPS};
  for (int i = 0; i < 16; ++i) {
    const int n = n0 + wave * 64 + i * 4 + g;
    const float4 q4 = *(const float4*)&qb[(size_t)n * cD + j * 4];
    float t2 = 0.f;
    t2 = fmaf(q4.x + kEPS, SkE[0], t2);
    t2 = fmaf(q4.y + kEPS, SkE[1], t2);
    t2 = fmaf(q4.z + kEPS, SkE[2], t2);
    t2 = fmaf(q4.w + kEPS, SkE[3], t2);
    #pragma unroll
    for (int off = 1; off < 16; off <<= 1) t2 += __shfl_xor(t2, off);
    const float sa_n = 1.f / (1.f + __expf(-(t2 + kEPS)));
    const float s = si[(size_t)bh * cN + n] * sa_n;
    ushort4 hh, ll;
    split2(q4.x * s, hh.x, ll.x);
    split2(q4.y * s, hh.y, ll.y);
    split2(q4.z * s, hh.z, ll.z);
    split2(q4.w * s, hh.w, ll.w);
    const size_t m = (size_t)b * cN + n;
    *(ushort4*)&xh[m * cC + head * 64 + j * 4] = hh;
    *(ushort4*)&xl[m * cC + head * 64 + j * 4] = ll;
  }
}

extern "C" void kernel_launch(void* const* d_in, const int* in_sizes, int n_in,
                              void* d_out, int out_size, void* d_ws, size_t ws_size,
                              hipStream_t stream) {
  (void)in_sizes; (void)n_in; (void)out_size;
  const float* x     = (const float*)d_in[0];
  const float* Wqkv  = (const float*)d_in[1];
  const float* Wproj = (const float*)d_in[2];
  const float* bproj = (const float*)d_in[3];
  float* out = (float*)d_out;
  float* ws  = (float*)d_ws;

  const size_t SLAB = (size_t)cBH * cN * cD;       // 16,777,216 floats (64 MB)
  const size_t OFF_Q   = 0;
  const size_t OFF_K   = SLAB;
  const size_t OFF_V   = 2 * SLAB;                 // xh/xl alias v (dead after K45)
  const size_t OFF_ACC = 3 * SLAB;
  const size_t ACC_FLOATS = 2048 * 4 + 32 + (size_t)cBH * cD * cD;  // 139,296
  const size_t OFF_R   = OFF_ACC + ACC_FLOATS;     // time-shared region
  const size_t R_FLOATS = (size_t)3 * cHD * cC;    // 786,432 floats (r8-proven fit)
  const size_t TOTAL   = OFF_R + R_FLOATS;
  if (ws_size < TOTAL * sizeof(float)) return;

  float* q    = ws + OFF_Q;
  float* k    = ws + OFF_K;
  float* v    = ws + OFF_V;
  float* ksum = ws + OFF_ACC;
  float* qsum = ksum + 2048;
  float* Sk   = ksum + 4096;
  float* Sq   = ksum + 6144;
  float* Zb   = ksum + 8192;
  float* kvm  = ksum + 8224;

  // region R timeline (786,432 floats):
  //   [0 .. 393216)         wq bf16 (786,432 ushorts)  alive: round_w -> gemm0
  //   [0 .. 262144)         si                          alive: k34 -> k6c (after gemm0)
  //   [262144 .. 786432)    kvw bf16 (1,048,576 ushorts) alive: kvw_build -> gemm1
  ushort* wq  = (ushort*)(ws + OFF_R);
  float*  si  = ws + OFF_R;
  ushort* kvw = (ushort*)(ws + OFF_R + (size_t)cBH * cN);   // +262144 floats
  // A' bf16 hi/lo overlay the v slab (v dead after K45)
  ushort* xh = (ushort*)(ws + OFF_V);
  ushort* xl = xh + (size_t)cM * cHD;

  // k45 split-K partials in d_out are legal: their lifetime (k45 -> k5r) ends
  // before gemm1 (the d_out writer) starts. gemm1 reads NOTHING from d_out.
  float* kvpart = out;                                   // 16 MB
  float* zpart  = out + (size_t)KV_SPLIT * cBH * 4096;   // 1024 floats

  hipMemsetAsync(ksum, 0, ACC_FLOATS * sizeof(float), stream);

  round_w<<<(3 * cHD * cC / 4 + 255) / 256, 256, 0, stream>>>(Wqkv, wq, 3 * cHD * cC / 4);
  gemm_mfma<0, 12><<<dim3(cM / 128, (3 * cHD) / 128), 256, 0, stream>>>(
      x, nullptr, nullptr, wq, 0, nullptr, q, k, v, qsum, ksum);
  k34_flow<<<dim3(cBH, cN / 256), 256, 0, stream>>>(q, k, qsum, ksum, si, Sq, Sk);
  k45_kv<<<dim3(cBH, KV_SPLIT), 256, 0, stream>>>(k, v, Sq, kvpart, zpart);
  k5r_reduce<<<dim3(cBH, 4), 256, 0, stream>>>(kvpart, zpart, kvm, Zb);
  kvw_build<<<dim3(cBH, 4), 256, 0, stream>>>(kvm, Wproj, Zb, kvw);
  k6c_scaleq<<<dim3(cBH, cN / 256), 256, 0, stream>>>(q, si, Sk, xh, xl);
  gemm_mfma<1, 4><<<dim3(cM / 128, cHD / 128), 256, 0, stream>>>(
      nullptr, xh, xl, kvw, cC * cHD, bproj, out, nullptr, nullptr, nullptr, nullptr);
}

// Round 11
// 261.776 us; speedup vs baseline: 2.3181x; 1.2956x over previous
//
#include <hip/hip_runtime.h>
#include <hip/hip_bf16.h>

typedef __attribute__((ext_vector_type(8))) short short8;
typedef __attribute__((ext_vector_type(4))) float f32x4;

constexpr int cB = 4, cN = 8192, cC = 512, cH = 8, cD = 64;
constexpr int cM = cB * cN;        // 32768 tokens
constexpr int cHD = cH * cD;       // 512
constexpr int cBH = cB * cH;       // 32
constexpr float kEPS = 1e-6f;
constexpr int KV_SPLIT = 32;       // k45 split-K slices

// ---- RNE f32 -> bf16 (unbiased) ----
__device__ __forceinline__ ushort rne_bf16(float f) {
  unsigned u = __float_as_uint(f);
  u += 0x7fffu + ((u >> 16) & 1u);
  return (ushort)(u >> 16);
}

// ---------------- rounder: f32 -> single bf16 (RNE); used for Wqkv and x ----------------
__global__ __launch_bounds__(256) void round_w(const float* __restrict__ src,
    ushort* __restrict__ w, int n4) {
  int i = blockIdx.x * 256 + threadIdx.x;
  if (i >= n4) return;
  float4 v = reinterpret_cast<const float4*>(src)[i];
  ushort4 h;
  h.x = rne_bf16(v.x); h.y = rne_bf16(v.y);
  h.z = rne_bf16(v.z); h.w = rne_bf16(v.w);
  reinterpret_cast<ushort4*>(w)[i] = h;
}

// ---------------- single-bf16 MFMA GEMM: C = A[Mx512] @ W[NCx512]^T ----------------
// m97 structure: per K-step 4 global_load_lds + 8 ds_read_b128 + 16 MFMA,
// single-buffer 16 KB LDS, 2 barriers/K-step.
// XOR-unit swizzle on stage+read (0 conflicts, r8) + bijective XCD swizzle (r8).
// EPI=0: epilogue scatters qkv (sigmoid q,k; v*0.125) + fused qsum/ksum.
// EPI=1: epilogue out = acc + bias. bstride = per-b B offset (kvW); 0 = shared.
// NOTE (r7 lesson): gemm1 (the d_out writer) reads NOTHING from d_out.
template<int EPI, int NY>
__global__ __launch_bounds__(256) void gemm_mfma(
    const ushort* __restrict__ Ab, const ushort* __restrict__ Wb, int bstride,
    const float* __restrict__ bias,
    float* __restrict__ o0, float* __restrict__ o1, float* __restrict__ o2,
    float* __restrict__ qsum, float* __restrict__ ksum) {
  constexpr int NT = cC / 32;                   // 16 K-steps of BK=32
  __shared__ ushort AhS[128 * 32];
  __shared__ ushort BhS[128 * 32];
  __shared__ float colsum[128];
  const int t = threadIdx.x;
  const int wave = t >> 6, lane = t & 63;
  const int wm = wave >> 1, wn = wave & 1;      // 2x2 waves of 64x64
  const int l15 = lane & 15, lg = lane >> 4;

  // ---- XCD-chunked bijective swizzle (nwg % 8 == 0 for both launches) ----
  const int raw = blockIdx.y * gridDim.x + blockIdx.x;
  const int q8 = (int)(gridDim.x * NY) >> 3;
  const int wg2 = (raw & 7) * q8 + (raw >> 3);
  const int rowchunk = wg2 / NY, ycol = wg2 - rowchunk * NY;
  const int row0 = rowchunk * 128, col0 = ycol * 128;
  const size_t wofs = (size_t)(row0 >> 13) * (size_t)bstride;  // per-b B offset

  if (EPI == 0 && t < 128) colsum[t] = 0.f;     // ordered by loop barriers

  f32x4 acc[4][4] = {};

  const int srow = lane >> 2, sunit = lane & 3; // glds stage mapping (4x16B/row)

#define STAGE_T(basep, base0, dst, k0)                                          \
  _Pragma("unroll")                                                             \
  for (int hh = 0; hh < 2; ++hh) {                                              \
    const int rr_ = wave * 32 + hh * 16 + srow;                                 \
    const int sw = sunit ^ ((rr_ >> 1) & 3);                                    \
    const size_t goff = (size_t)(base0 + rr_) * cC + (k0) + sw * 8;             \
    __builtin_amdgcn_global_load_lds(                                           \
        (const __attribute__((address_space(1))) void*)(basep + goff),          \
        (__attribute__((address_space(3))) void*)(&dst[(wave * 32 + hh * 16) * 32]), \
        16, 0, 0);                                                              \
  }

  for (int kt = 0; kt < NT; ++kt) {
    // ---- stage tile kt into LDS (A + B, single bf16 each) ----
    STAGE_T(Ab, row0, AhS, kt * 32);
    STAGE_T((Wb + wofs), col0, BhS, kt * 32);
    __syncthreads();
    // ---- fragments + MFMA ----
    short8 ah[4];
    #pragma unroll
    for (int mi = 0; mi < 4; ++mi) {
      const int r = wm * 64 + mi * 16 + l15;
      ah[mi] = *reinterpret_cast<const short8*>(&AhS[r * 32 + (lg ^ ((r >> 1) & 3)) * 8]);
    }
    #pragma unroll
    for (int ni = 0; ni < 4; ++ni) {
      const int c = wn * 64 + ni * 16 + l15;
      const short8 bh = *reinterpret_cast<const short8*>(&BhS[c * 32 + (lg ^ ((c >> 1) & 3)) * 8]);
      #pragma unroll
      for (int mi = 0; mi < 4; ++mi)
        acc[mi][ni] = __builtin_amdgcn_mfma_f32_16x16x32_bf16(ah[mi], bh, acc[mi][ni], 0, 0, 0);
    }
    __syncthreads();                           // MFMA reads done before overwrite
  }
#undef STAGE_T

  // ---- epilogue: C/D map col=lane&15, row=(lane>>4)*4+r ----
  const bool qk_block = (EPI == 0) && (ycol < 8);
  float csum[4] = {};
  #pragma unroll
  for (int mi = 0; mi < 4; ++mi) {
    #pragma unroll
    for (int ni = 0; ni < 4; ++ni) {
      const int col = col0 + wn * 64 + ni * 16 + l15;
      #pragma unroll
      for (int r = 0; r < 4; ++r) {
        const int m = row0 + wm * 64 + mi * 16 + lg * 4 + r;
        const float val = acc[mi][ni][r];
        if (EPI == 0) {
          const int which = col >> 9;
          const int c2 = col & 511;
          const int h = c2 >> 6, d = c2 & 63;
          const int bb = m >> 13, n = m & 8191;
          const size_t idx = (((size_t)(bb * cH + h)) * cN + n) * cD + d;
          if (which < 2) {
            const float sv = 1.f / (1.f + __expf(-val));
            if (which == 0) o0[idx] = sv; else o1[idx] = sv;
            csum[ni] += sv;
          } else {
            o2[idx] = val * 0.125f;
          }
        } else {
          o0[(size_t)m * cC + col] = val + bias[col];
        }
      }
    }
  }
  if (qk_block) {
    #pragma unroll
    for (int ni = 0; ni < 4; ++ni)
      atomicAdd(&colsum[wn * 64 + ni * 16 + l15], csum[ni]);
    __syncthreads();
    if (t < 128) {
      const int col = col0 + t;
      const int c2 = col & 511;
      const int h = c2 >> 6, d = c2 & 63;
      const int bb = row0 >> 13;
      float* tgt = (col < 512) ? qsum : ksum;
      atomicAdd(&tgt[(bb * cH + h) * cD + d], colsum[t]);
    }
  }
}

// ---------------- K34: si, so; accumulate Sq, Sk (4 rows/wave/iter, float4) ----------------
__global__ __launch_bounds__(256) void k34_flow(const float* __restrict__ q,
      const float* __restrict__ k, const float* __restrict__ qsum,
      const float* __restrict__ ksum, float* __restrict__ si,
      float* __restrict__ Sq, float* __restrict__ Sk) {
  const int bh = blockIdx.x;
  const int n0 = blockIdx.y * 256;
  const int t = threadIdx.x;
  const int wave = t >> 6, lane = t & 63;
  const int g = lane >> 4, j = lane & 15;
  const float* qb = q + (size_t)bh * cN * cD;
  const float* kb = k + (size_t)bh * cN * cD;
  const float4 ks4 = *(const float4*)&ksum[bh * 64 + j * 4];
  const float4 qs4 = *(const float4*)&qsum[bh * 64 + j * 4];
  const float ksd[4] = {ks4.x + kEPS, ks4.y + kEPS, ks4.z + kEPS, ks4.w + kEPS};
  const float qsd[4] = {qs4.x + kEPS, qs4.y + kEPS, qs4.z + kEPS, qs4.w + kEPS};
  float aSq[4] = {}, aSk[4] = {};
  for (int i = 0; i < 16; ++i) {
    const int n = n0 + wave * 64 + i * 4 + g;
    const float4 q4 = *(const float4*)&qb[(size_t)n * cD + j * 4];
    const float4 k4 = *(const float4*)&kb[(size_t)n * cD + j * 4];
    const float qa[4] = {q4.x, q4.y, q4.z, q4.w};
    const float ka[4] = {k4.x, k4.y, k4.z, k4.w};
    float t1 = 0.f, t2 = 0.f;
    #pragma unroll
    for (int c = 0; c < 4; ++c) {
      t1 = fmaf(qa[c] + kEPS, ksd[c], t1);
      t2 = fmaf(ka[c] + kEPS, qsd[c], t2);
    }
    #pragma unroll
    for (int off = 1; off < 16; off <<= 1) {
      t1 += __shfl_xor(t1, off);
      t2 += __shfl_xor(t2, off);
    }
    const float si_n = 1.f / (t1 + kEPS);
    const float so_n = 1.f / (t2 + kEPS);
    if (j == 0) si[(size_t)bh * cN + n] = si_n;
    #pragma unroll
    for (int c = 0; c < 4; ++c) {
      aSq[c] = fmaf(qa[c], si_n, aSq[c]);
      aSk[c] = fmaf(ka[c], so_n, aSk[c]);
    }
  }
  #pragma unroll
  for (int c = 0; c < 4; ++c) {
    aSq[c] += __shfl_xor(aSq[c], 16); aSq[c] += __shfl_xor(aSq[c], 32);
    aSk[c] += __shfl_xor(aSk[c], 16); aSk[c] += __shfl_xor(aSk[c], 32);
  }
  __shared__ float sAq[4][64], sAk[4][64];
  if (g == 0) {
    #pragma unroll
    for (int c = 0; c < 4; ++c) { sAq[wave][j * 4 + c] = aSq[c]; sAk[wave][j * 4 + c] = aSk[c]; }
  }
  __syncthreads();
  if (t < 64) {
    atomicAdd(&Sq[bh * 64 + t], sAq[0][t] + sAq[1][t] + sAq[2][t] + sAq[3][t]);
    atomicAdd(&Sk[bh * 64 + t], sAk[0][t] + sAk[1][t] + sAk[2][t] + sAk[3][t]);
  }
}

// ---------------- K45: split-K kv partials (NO atomics), ev inline ----------------
__global__ __launch_bounds__(256) void k45_kv(const float* __restrict__ kk_,
      const float* __restrict__ vv, const float* __restrict__ Sq,
      float* __restrict__ kvpart, float* __restrict__ zpart) {
  const int bh = blockIdx.x;
  const int y = blockIdx.y;                       // KV_SPLIT slices
  constexpr int ROWS = cN / KV_SPLIT;             // 256
  const int n0 = y * ROWS;
  const int t = threadIdx.x;
  const int d = t & 63, eb = t >> 6;
  const int g = t >> 4, j = t & 15;               // 16 ev-groups of 16 lanes
  const int sr = t >> 4, sc = (t & 15) * 4;       // stage mapping
  const float* kb = kk_ + (size_t)bh * cN * cD;
  const float* vb = vv + (size_t)bh * cN * cD;
  const float4 sq4 = *(const float4*)&Sq[bh * 64 + j * 4];
  const float SqE[4] = {sq4.x + kEPS, sq4.y + kEPS, sq4.z + kEPS, sq4.w + kEPS};
  __shared__ float ks[32][64];
  __shared__ float vs[32][64];
  __shared__ float evs[32];
  __shared__ float zl[16];
  float acc[16] = {};
  float zacc = 0.f;
  float4 pk0 = *(const float4*)&kb[(size_t)(n0 + sr) * cD + sc];
  float4 pk1 = *(const float4*)&kb[(size_t)(n0 + 16 + sr) * cD + sc];
  float4 pv0 = *(const float4*)&vb[(size_t)(n0 + sr) * cD + sc];
  float4 pv1 = *(const float4*)&vb[(size_t)(n0 + 16 + sr) * cD + sc];
  for (int c0 = 0; c0 < ROWS; c0 += 32) {
    __syncthreads();
    *(float4*)&ks[sr][sc]      = pk0;
    *(float4*)&ks[sr + 16][sc] = pk1;
    *(float4*)&vs[sr][sc]      = pv0;
    *(float4*)&vs[sr + 16][sc] = pv1;
    __syncthreads();
    if (c0 + 32 < ROWS) {
      pk0 = *(const float4*)&kb[(size_t)(n0 + c0 + 32 + sr) * cD + sc];
      pk1 = *(const float4*)&kb[(size_t)(n0 + c0 + 48 + sr) * cD + sc];
      pv0 = *(const float4*)&vb[(size_t)(n0 + c0 + 32 + sr) * cD + sc];
      pv1 = *(const float4*)&vb[(size_t)(n0 + c0 + 48 + sr) * cD + sc];
    }
    #pragma unroll
    for (int rr = 0; rr < 2; ++rr) {
      const int r = g * 2 + rr;
      const float4 kk4 = *(const float4*)&ks[r][j * 4];
      float tt = 0.f;
      tt = fmaf(kk4.x + kEPS, SqE[0], tt);
      tt = fmaf(kk4.y + kEPS, SqE[1], tt);
      tt = fmaf(kk4.z + kEPS, SqE[2], tt);
      tt = fmaf(kk4.w + kEPS, SqE[3], tt);
      #pragma unroll
      for (int off = 1; off < 16; off <<= 1) tt += __shfl_xor(tt, off);
      if (j == 0) {
        const float cs = fminf(fmaxf(tt + kEPS, -1.f), 1.f);
        const float e = __expf(cs);
        evs[r] = e;
        zacc += e;
      }
    }
    __syncthreads();
    #pragma unroll
    for (int r = 0; r < 32; ++r) {
      const float kd = ks[r][d] * evs[r];
      #pragma unroll
      for (int j2 = 0; j2 < 16; ++j2)
        acc[j2] = fmaf(kd, vs[r][eb * 16 + j2], acc[j2]);
    }
  }
  if (j == 0) zl[g] = zacc;
  __syncthreads();
  if (t == 0) {
    float z = 0.f;
    #pragma unroll
    for (int i = 0; i < 16; ++i) z += zl[i];
    zpart[y * cBH + bh] = z;
  }
  float* kvb = kvpart + ((size_t)y * cBH + bh) * 4096 + d * 64 + eb * 16;
  #pragma unroll
  for (int j2 = 0; j2 < 16; ++j2) kvb[j2] = acc[j2];
}

// ---------------- K5R: fold split-K partials -> kvm, Zb (deterministic) ----------------
__global__ __launch_bounds__(256) void k5r_reduce(const float* __restrict__ kvpart,
      const float* __restrict__ zpart, float* __restrict__ kvm, float* __restrict__ Zb) {
  const int bh = blockIdx.x;
  const int yq = blockIdx.y;                      // 4 chunks of 1024
  const int t = threadIdx.x;
  for (int i = yq * 1024 + t; i < (yq + 1) * 1024; i += 256) {
    float s = 0.f;
    #pragma unroll
    for (int yy = 0; yy < KV_SPLIT; ++yy)
      s += kvpart[((size_t)yy * cBH + bh) * 4096 + i];
    kvm[(size_t)bh * 4096 + i] = s;
  }
  if (yq == 0 && t == 0) {
    float z = 0.f;
    #pragma unroll
    for (int yy = 0; yy < KV_SPLIT; ++yy) z += zpart[yy * cBH + bh];
    Zb[bh] = z;
  }
}

// ---------------- KVW: kvw[b][c*512 + h*64+d] = RNE( (N/Z)·(kv_bh @ Wproj_h^T)[d,c] ) ----------------
__global__ __launch_bounds__(256) void kvw_build(const float* __restrict__ kvm,
      const float* __restrict__ Wproj, const float* __restrict__ Zb,
      ushort* __restrict__ kvw) {
  const int bh = blockIdx.x;                     // 32
  const int c0 = blockIdx.y * 128;               // 4 c-chunks
  const int b = bh >> 3, h = bh & 7;
  const int t = threadIdx.x;
  __shared__ float kvs[64][64];
  for (int i = t; i < 4096; i += 256)
    kvs[i >> 6][i & 63] = kvm[(size_t)bh * 4096 + i];
  __syncthreads();
  const float zs = (float)cN / Zb[bh];
  const int cl = t & 127, half = t >> 7;         // c-local, d-half
  const int c = c0 + cl;
  float acc[32] = {};
  for (int ec = 0; ec < 64; ec += 8) {
    float w[8];
    #pragma unroll
    for (int e = 0; e < 8; ++e)
      w[e] = Wproj[(size_t)c * cHD + h * 64 + ec + e];
    #pragma unroll
    for (int d = 0; d < 32; ++d)
      #pragma unroll
      for (int e = 0; e < 8; ++e)
        acc[d] = fmaf(kvs[half * 32 + d][ec + e], w[e], acc[d]);
  }
  ushort* dst = kvw + (size_t)b * cC * cHD + (size_t)c * cC + h * 64 + half * 32;
  #pragma unroll
  for (int d = 0; d < 32; ++d) dst[d] = rne_bf16(acc[d] * zs);
}

// ---------------- K6c: A' = RNE_bf16( q · si · sa ), [M][512] token-major ----------------
__global__ __launch_bounds__(256) void k6c_scaleq(const float* __restrict__ q,
      const float* __restrict__ si, const float* __restrict__ Sk,
      ushort* __restrict__ xq) {
  const int bh = blockIdx.x;
  const int b = bh >> 3, head = bh & 7;
  const int n0 = blockIdx.y * 256;
  const int t = threadIdx.x;
  const int wave = t >> 6, lane = t & 63;
  const int g = lane >> 4, j = lane & 15;
  const float* qb = q + (size_t)bh * cN * cD;
  const float4 sk4 = *(const float4*)&Sk[bh * 64 + j * 4];
  const float SkE[4] = {sk4.x + kEPS, sk4.y + kEPS, sk4.z + kEPS, sk4.w + kEPS};
  for (int i = 0; i < 16; ++i) {
    const int n = n0 + wave * 64 + i * 4 + g;
    const float4 q4 = *(const float4*)&qb[(size_t)n * cD + j * 4];
    float t2 = 0.f;
    t2 = fmaf(q4.x + kEPS, SkE[0], t2);
    t2 = fmaf(q4.y + kEPS, SkE[1], t2);
    t2 = fmaf(q4.z + kEPS, SkE[2], t2);
    t2 = fmaf(q4.w + kEPS, SkE[3], t2);
    #pragma unroll
    for (int off = 1; off < 16; off <<= 1) t2 += __shfl_xor(t2, off);
    const float sa_n = 1.f / (1.f + __expf(-(t2 + kEPS)));
    const float s = si[(size_t)bh * cN + n] * sa_n;
    ushort4 hh;
    hh.x = rne_bf16(q4.x * s);
    hh.y = rne_bf16(q4.y * s);
    hh.z = rne_bf16(q4.z * s);
    hh.w = rne_bf16(q4.w * s);
    const size_t m = (size_t)b * cN + n;
    *(ushort4*)&xq[m * cC + head * 64 + j * 4] = hh;
  }
}

extern "C" void kernel_launch(void* const* d_in, const int* in_sizes, int n_in,
                              void* d_out, int out_size, void* d_ws, size_t ws_size,
                              hipStream_t stream) {
  (void)in_sizes; (void)n_in; (void)out_size;
  const float* x     = (const float*)d_in[0];
  const float* Wqkv  = (const float*)d_in[1];
  const float* Wproj = (const float*)d_in[2];
  const float* bproj = (const float*)d_in[3];
  float* out = (float*)d_out;
  float* ws  = (float*)d_ws;

  const size_t SLAB = (size_t)cBH * cN * cD;       // 16,777,216 floats (64 MB)
  const size_t OFF_Q   = 0;
  const size_t OFF_K   = SLAB;
  const size_t OFF_V   = 2 * SLAB;                 // xq aliases v (dead after K45)
  const size_t OFF_ACC = 3 * SLAB;
  const size_t ACC_FLOATS = 2048 * 4 + 32 + (size_t)cBH * cD * cD;  // 139,296
  const size_t OFF_R   = OFF_ACC + ACC_FLOATS;     // time-shared region
  const size_t R_FLOATS = (size_t)3 * cHD * cC;    // 786,432 floats (r8-proven fit)
  const size_t TOTAL   = OFF_R + R_FLOATS;
  if (ws_size < TOTAL * sizeof(float)) return;

  float* q    = ws + OFF_Q;
  float* k    = ws + OFF_K;
  float* v    = ws + OFF_V;
  float* ksum = ws + OFF_ACC;
  float* qsum = ksum + 2048;
  float* Sk   = ksum + 4096;
  float* Sq   = ksum + 6144;
  float* Zb   = ksum + 8192;
  float* kvm  = ksum + 8224;

  // region R timeline (786,432 floats):
  //   [0 .. 393216)         wq bf16 (786,432 ushorts)    alive: round_w -> gemm0
  //   [0 .. 262144)         si                            alive: k34 -> k6c (after gemm0)
  //   [262144 .. 786432)    kvw bf16 (1,048,576 ushorts)  alive: kvw_build -> gemm1
  ushort* wq  = (ushort*)(ws + OFF_R);
  float*  si  = ws + OFF_R;
  ushort* kvw = (ushort*)(ws + OFF_R + (size_t)cBH * cN);   // +262144 floats
  // A' single-bf16 overlays the v slab (v dead after K45)
  ushort* xq = (ushort*)(ws + OFF_V);

  // d_out scratch timeline (gemm1 writes ALL of d_out last, reads none of it):
  //   xs bf16 [0 .. 8M floats)       alive: round_w(x) -> gemm0
  //   kvpart  [8M .. 12M floats)     alive: k45 -> k5r
  //   zpart   [12M .. 12M+1K)        alive: k45 -> k5r
  ushort* xs    = (ushort*)out;                          // 16M ushorts = 32 MB
  float* kvpart = out + (size_t)8 * 1024 * 1024;
  float* zpart  = kvpart + (size_t)KV_SPLIT * cBH * 4096;

  hipMemsetAsync(ksum, 0, ACC_FLOATS * sizeof(float), stream);

  round_w<<<(3 * cHD * cC / 4 + 255) / 256, 256, 0, stream>>>(Wqkv, wq, 3 * cHD * cC / 4);
  round_w<<<((size_t)cM * cC / 4 + 255) / 256, 256, 0, stream>>>(x, xs, cM * cC / 4);
  gemm_mfma<0, 12><<<dim3(cM / 128, (3 * cHD) / 128), 256, 0, stream>>>(
      xs, wq, 0, nullptr, q, k, v, qsum, ksum);
  k34_flow<<<dim3(cBH, cN / 256), 256, 0, stream>>>(q, k, qsum, ksum, si, Sq, Sk);
  k45_kv<<<dim3(cBH, KV_SPLIT), 256, 0, stream>>>(k, v, Sq, kvpart, zpart);
  k5r_reduce<<<dim3(cBH, 4), 256, 0, stream>>>(kvpart, zpart, kvm, Zb);
  kvw_build<<<dim3(cBH, 4), 256, 0, stream>>>(kvm, Wproj, Zb, kvw);
  k6c_scaleq<<<dim3(cBH, cN / 256), 256, 0, stream>>>(q, si, Sk, xq);
  gemm_mfma<1, 4><<<dim3(cM / 128, cHD / 128), 256, 0, stream>>>(
      xq, kvw, cC * cHD, bproj, out, nullptr, nullptr, nullptr, nullptr);
}

// Round 12
// 242.430 us; speedup vs baseline: 2.5031x; 1.0798x over previous
//
#include <hip/hip_runtime.h>
#include <hip/hip_bf16.h>

typedef __attribute__((ext_vector_type(8))) short short8;
typedef __attribute__((ext_vector_type(4))) float f32x4;

constexpr int cB = 4, cN = 8192, cC = 512, cH = 8, cD = 64;
constexpr int cM = cB * cN;        // 32768 tokens
constexpr int cHD = cH * cD;       // 512
constexpr int cBH = cB * cH;       // 32
constexpr float kEPS = 1e-6f;
constexpr int KV_SPLIT = 32;       // k45 split-K slices

// ---- RNE f32 -> bf16 (unbiased) ----
__device__ __forceinline__ ushort rne_bf16(float f) {
  unsigned u = __float_as_uint(f);
  u += 0x7fffu + ((u >> 16) & 1u);
  return (ushort)(u >> 16);
}
__device__ __forceinline__ float b2f(ushort u) {
  return __uint_as_float((unsigned)u << 16);
}

// ---------------- rounder: f32 -> single bf16 (RNE); used for Wqkv and x ----------------
__global__ __launch_bounds__(256) void round_w(const float* __restrict__ src,
    ushort* __restrict__ w, int n4) {
  int i = blockIdx.x * 256 + threadIdx.x;
  if (i >= n4) return;
  float4 v = reinterpret_cast<const float4*>(src)[i];
  ushort4 h;
  h.x = rne_bf16(v.x); h.y = rne_bf16(v.y);
  h.z = rne_bf16(v.z); h.w = rne_bf16(v.w);
  reinterpret_cast<ushort4*>(w)[i] = h;
}

// ---------------- single-bf16 MFMA GEMM: C = A[Mx512] @ W[NCx512]^T ----------------
// m97 structure: per K-step 4 global_load_lds + 8 ds_read_b128 + 16 MFMA,
// single-buffer 16 KB LDS, 2 barriers/K-step.
// XOR-unit swizzle on stage+read (0 conflicts, r8) + bijective XCD swizzle (r8).
// EPI=0: epilogue scatters qkv as RNE-bf16 (sigmoid q,k; v*0.125) + fused qsum/ksum
//        (sums accumulate pre-rounding f32).
// EPI=1: epilogue out = acc + bias (f32). bstride = per-b B offset (kvW).
// NOTE (r7 lesson): gemm1 (the d_out writer) reads NOTHING from d_out.
template<int EPI, int NY>
__global__ __launch_bounds__(256) void gemm_mfma(
    const ushort* __restrict__ Ab, const ushort* __restrict__ Wb, int bstride,
    const float* __restrict__ bias,
    void* __restrict__ o0v, void* __restrict__ o1v, void* __restrict__ o2v,
    float* __restrict__ qsum, float* __restrict__ ksum) {
  constexpr int NT = cC / 32;                   // 16 K-steps of BK=32
  __shared__ ushort AhS[128 * 32];
  __shared__ ushort BhS[128 * 32];
  __shared__ float colsum[128];
  const int t = threadIdx.x;
  const int wave = t >> 6, lane = t & 63;
  const int wm = wave >> 1, wn = wave & 1;      // 2x2 waves of 64x64
  const int l15 = lane & 15, lg = lane >> 4;

  // ---- XCD-chunked bijective swizzle (nwg % 8 == 0 for both launches) ----
  const int raw = blockIdx.y * gridDim.x + blockIdx.x;
  const int q8 = (int)(gridDim.x * NY) >> 3;
  const int wg2 = (raw & 7) * q8 + (raw >> 3);
  const int rowchunk = wg2 / NY, ycol = wg2 - rowchunk * NY;
  const int row0 = rowchunk * 128, col0 = ycol * 128;
  const size_t wofs = (size_t)(row0 >> 13) * (size_t)bstride;  // per-b B offset

  if (EPI == 0 && t < 128) colsum[t] = 0.f;     // ordered by loop barriers

  f32x4 acc[4][4] = {};

  const int srow = lane >> 2, sunit = lane & 3; // glds stage mapping (4x16B/row)

#define STAGE_T(basep, base0, dst, k0)                                          \
  _Pragma("unroll")                                                             \
  for (int hh = 0; hh < 2; ++hh) {                                              \
    const int rr_ = wave * 32 + hh * 16 + srow;                                 \
    const int sw = sunit ^ ((rr_ >> 1) & 3);                                    \
    const size_t goff = (size_t)(base0 + rr_) * cC + (k0) + sw * 8;             \
    __builtin_amdgcn_global_load_lds(                                           \
        (const __attribute__((address_space(1))) void*)(basep + goff),          \
        (__attribute__((address_space(3))) void*)(&dst[(wave * 32 + hh * 16) * 32]), \
        16, 0, 0);                                                              \
  }

  for (int kt = 0; kt < NT; ++kt) {
    STAGE_T(Ab, row0, AhS, kt * 32);
    STAGE_T((Wb + wofs), col0, BhS, kt * 32);
    __syncthreads();
    short8 ah[4];
    #pragma unroll
    for (int mi = 0; mi < 4; ++mi) {
      const int r = wm * 64 + mi * 16 + l15;
      ah[mi] = *reinterpret_cast<const short8*>(&AhS[r * 32 + (lg ^ ((r >> 1) & 3)) * 8]);
    }
    #pragma unroll
    for (int ni = 0; ni < 4; ++ni) {
      const int c = wn * 64 + ni * 16 + l15;
      const short8 bh = *reinterpret_cast<const short8*>(&BhS[c * 32 + (lg ^ ((c >> 1) & 3)) * 8]);
      #pragma unroll
      for (int mi = 0; mi < 4; ++mi)
        acc[mi][ni] = __builtin_amdgcn_mfma_f32_16x16x32_bf16(ah[mi], bh, acc[mi][ni], 0, 0, 0);
    }
    __syncthreads();
  }
#undef STAGE_T

  // ---- epilogue: C/D map col=lane&15, row=(lane>>4)*4+r ----
  const bool qk_block = (EPI == 0) && (ycol < 8);
  float csum[4] = {};
  #pragma unroll
  for (int mi = 0; mi < 4; ++mi) {
    #pragma unroll
    for (int ni = 0; ni < 4; ++ni) {
      const int col = col0 + wn * 64 + ni * 16 + l15;
      #pragma unroll
      for (int r = 0; r < 4; ++r) {
        const int m = row0 + wm * 64 + mi * 16 + lg * 4 + r;
        const float val = acc[mi][ni][r];
        if (EPI == 0) {
          const int which = col >> 9;
          const int c2 = col & 511;
          const int h = c2 >> 6, d = c2 & 63;
          const int bb = m >> 13, n = m & 8191;
          const size_t idx = (((size_t)(bb * cH + h)) * cN + n) * cD + d;
          if (which < 2) {
            const float sv = 1.f / (1.f + __expf(-val));
            if (which == 0) ((ushort*)o0v)[idx] = rne_bf16(sv);
            else            ((ushort*)o1v)[idx] = rne_bf16(sv);
            csum[ni] += sv;
          } else {
            ((ushort*)o2v)[idx] = rne_bf16(val * 0.125f);
          }
        } else {
          ((float*)o0v)[(size_t)m * cC + col] = val + bias[col];
        }
      }
    }
  }
  if (qk_block) {
    #pragma unroll
    for (int ni = 0; ni < 4; ++ni)
      atomicAdd(&colsum[wn * 64 + ni * 16 + l15], csum[ni]);
    __syncthreads();
    if (t < 128) {
      const int col = col0 + t;
      const int c2 = col & 511;
      const int h = c2 >> 6, d = c2 & 63;
      const int bb = row0 >> 13;
      float* tgt = (col < 512) ? qsum : ksum;
      atomicAdd(&tgt[(bb * cH + h) * cD + d], colsum[t]);
    }
  }
}

// ---------------- K34: si, so; accumulate Sq, Sk (bf16 q/k inputs) ----------------
__global__ __launch_bounds__(256) void k34_flow(const ushort* __restrict__ q,
      const ushort* __restrict__ k, const float* __restrict__ qsum,
      const float* __restrict__ ksum, float* __restrict__ si,
      float* __restrict__ Sq, float* __restrict__ Sk) {
  const int bh = blockIdx.x;
  const int n0 = blockIdx.y * 256;
  const int t = threadIdx.x;
  const int wave = t >> 6, lane = t & 63;
  const int g = lane >> 4, j = lane & 15;
  const ushort* qb = q + (size_t)bh * cN * cD;
  const ushort* kb = k + (size_t)bh * cN * cD;
  const float4 ks4 = *(const float4*)&ksum[bh * 64 + j * 4];
  const float4 qs4 = *(const float4*)&qsum[bh * 64 + j * 4];
  const float ksd[4] = {ks4.x + kEPS, ks4.y + kEPS, ks4.z + kEPS, ks4.w + kEPS};
  const float qsd[4] = {qs4.x + kEPS, qs4.y + kEPS, qs4.z + kEPS, qs4.w + kEPS};
  float aSq[4] = {}, aSk[4] = {};
  for (int i = 0; i < 16; ++i) {
    const int n = n0 + wave * 64 + i * 4 + g;
    const ushort4 qu = *(const ushort4*)&qb[(size_t)n * cD + j * 4];
    const ushort4 ku = *(const ushort4*)&kb[(size_t)n * cD + j * 4];
    const float qa[4] = {b2f(qu.x), b2f(qu.y), b2f(qu.z), b2f(qu.w)};
    const float ka[4] = {b2f(ku.x), b2f(ku.y), b2f(ku.z), b2f(ku.w)};
    float t1 = 0.f, t2 = 0.f;
    #pragma unroll
    for (int c = 0; c < 4; ++c) {
      t1 = fmaf(qa[c] + kEPS, ksd[c], t1);
      t2 = fmaf(ka[c] + kEPS, qsd[c], t2);
    }
    #pragma unroll
    for (int off = 1; off < 16; off <<= 1) {
      t1 += __shfl_xor(t1, off);
      t2 += __shfl_xor(t2, off);
    }
    const float si_n = 1.f / (t1 + kEPS);
    const float so_n = 1.f / (t2 + kEPS);
    if (j == 0) si[(size_t)bh * cN + n] = si_n;
    #pragma unroll
    for (int c = 0; c < 4; ++c) {
      aSq[c] = fmaf(qa[c], si_n, aSq[c]);
      aSk[c] = fmaf(ka[c], so_n, aSk[c]);
    }
  }
  #pragma unroll
  for (int c = 0; c < 4; ++c) {
    aSq[c] += __shfl_xor(aSq[c], 16); aSq[c] += __shfl_xor(aSq[c], 32);
    aSk[c] += __shfl_xor(aSk[c], 16); aSk[c] += __shfl_xor(aSk[c], 32);
  }
  __shared__ float sAq[4][64], sAk[4][64];
  if (g == 0) {
    #pragma unroll
    for (int c = 0; c < 4; ++c) { sAq[wave][j * 4 + c] = aSq[c]; sAk[wave][j * 4 + c] = aSk[c]; }
  }
  __syncthreads();
  if (t < 64) {
    atomicAdd(&Sq[bh * 64 + t], sAq[0][t] + sAq[1][t] + sAq[2][t] + sAq[3][t]);
    atomicAdd(&Sk[bh * 64 + t], sAk[0][t] + sAk[1][t] + sAk[2][t] + sAk[3][t]);
  }
}

// ---------------- K45: split-K kv partials (NO atomics), ev inline; bf16 k/v in ----------------
__global__ __launch_bounds__(256) void k45_kv(const ushort* __restrict__ kk_,
      const ushort* __restrict__ vv, const float* __restrict__ Sq,
      float* __restrict__ kvpart, float* __restrict__ zpart) {
  const int bh = blockIdx.x;
  const int y = blockIdx.y;                       // KV_SPLIT slices
  constexpr int ROWS = cN / KV_SPLIT;             // 256
  const int n0 = y * ROWS;
  const int t = threadIdx.x;
  const int d = t & 63, eb = t >> 6;
  const int g = t >> 4, j = t & 15;               // 16 ev-groups of 16 lanes
  const int sr = t >> 4, sc = (t & 15) * 4;       // stage mapping
  const ushort* kb = kk_ + (size_t)bh * cN * cD;
  const ushort* vb = vv + (size_t)bh * cN * cD;
  const float4 sq4 = *(const float4*)&Sq[bh * 64 + j * 4];
  const float SqE[4] = {sq4.x + kEPS, sq4.y + kEPS, sq4.z + kEPS, sq4.w + kEPS};
  __shared__ float ks[32][64];
  __shared__ float vs[32][64];
  __shared__ float evs[32];
  __shared__ float zl[16];
  float acc[16] = {};
  float zacc = 0.f;
  ushort4 pk0 = *(const ushort4*)&kb[(size_t)(n0 + sr) * cD + sc];
  ushort4 pk1 = *(const ushort4*)&kb[(size_t)(n0 + 16 + sr) * cD + sc];
  ushort4 pv0 = *(const ushort4*)&vb[(size_t)(n0 + sr) * cD + sc];
  ushort4 pv1 = *(const ushort4*)&vb[(size_t)(n0 + 16 + sr) * cD + sc];
  for (int c0 = 0; c0 < ROWS; c0 += 32) {
    __syncthreads();
    *(float4*)&ks[sr][sc]      = make_float4(b2f(pk0.x), b2f(pk0.y), b2f(pk0.z), b2f(pk0.w));
    *(float4*)&ks[sr + 16][sc] = make_float4(b2f(pk1.x), b2f(pk1.y), b2f(pk1.z), b2f(pk1.w));
    *(float4*)&vs[sr][sc]      = make_float4(b2f(pv0.x), b2f(pv0.y), b2f(pv0.z), b2f(pv0.w));
    *(float4*)&vs[sr + 16][sc] = make_float4(b2f(pv1.x), b2f(pv1.y), b2f(pv1.z), b2f(pv1.w));
    __syncthreads();
    if (c0 + 32 < ROWS) {
      pk0 = *(const ushort4*)&kb[(size_t)(n0 + c0 + 32 + sr) * cD + sc];
      pk1 = *(const ushort4*)&kb[(size_t)(n0 + c0 + 48 + sr) * cD + sc];
      pv0 = *(const ushort4*)&vb[(size_t)(n0 + c0 + 32 + sr) * cD + sc];
      pv1 = *(const ushort4*)&vb[(size_t)(n0 + c0 + 48 + sr) * cD + sc];
    }
    #pragma unroll
    for (int rr = 0; rr < 2; ++rr) {
      const int r = g * 2 + rr;
      const float4 kk4 = *(const float4*)&ks[r][j * 4];
      float tt = 0.f;
      tt = fmaf(kk4.x + kEPS, SqE[0], tt);
      tt = fmaf(kk4.y + kEPS, SqE[1], tt);
      tt = fmaf(kk4.z + kEPS, SqE[2], tt);
      tt = fmaf(kk4.w + kEPS, SqE[3], tt);
      #pragma unroll
      for (int off = 1; off < 16; off <<= 1) tt += __shfl_xor(tt, off);
      if (j == 0) {
        const float cs = fminf(fmaxf(tt + kEPS, -1.f), 1.f);
        const float e = __expf(cs);
        evs[r] = e;
        zacc += e;
      }
    }
    __syncthreads();
    #pragma unroll
    for (int r = 0; r < 32; ++r) {
      const float kd = ks[r][d] * evs[r];
      #pragma unroll
      for (int j2 = 0; j2 < 16; ++j2)
        acc[j2] = fmaf(kd, vs[r][eb * 16 + j2], acc[j2]);
    }
  }
  if (j == 0) zl[g] = zacc;
  __syncthreads();
  if (t == 0) {
    float z = 0.f;
    #pragma unroll
    for (int i = 0; i < 16; ++i) z += zl[i];
    zpart[y * cBH + bh] = z;
  }
  float* kvb = kvpart + ((size_t)y * cBH + bh) * 4096 + d * 64 + eb * 16;
  #pragma unroll
  for (int j2 = 0; j2 < 16; ++j2) kvb[j2] = acc[j2];
}

// ---------------- K5R: fold split-K partials -> kvm, Zb (deterministic) ----------------
__global__ __launch_bounds__(256) void k5r_reduce(const float* __restrict__ kvpart,
      const float* __restrict__ zpart, float* __restrict__ kvm, float* __restrict__ Zb) {
  const int bh = blockIdx.x;
  const int yq = blockIdx.y;                      // 4 chunks of 1024
  const int t = threadIdx.x;
  for (int i = yq * 1024 + t; i < (yq + 1) * 1024; i += 256) {
    float s = 0.f;
    #pragma unroll
    for (int yy = 0; yy < KV_SPLIT; ++yy)
      s += kvpart[((size_t)yy * cBH + bh) * 4096 + i];
    kvm[(size_t)bh * 4096 + i] = s;
  }
  if (yq == 0 && t == 0) {
    float z = 0.f;
    #pragma unroll
    for (int yy = 0; yy < KV_SPLIT; ++yy) z += zpart[yy * cBH + bh];
    Zb[bh] = z;
  }
}

// ---------------- KVW: kvw[b][c*512 + h*64+d] = RNE( (N/Z)·(kv_bh @ Wproj_h^T)[d,c] ) ----------------
__global__ __launch_bounds__(256) void kvw_build(const float* __restrict__ kvm,
      const float* __restrict__ Wproj, const float* __restrict__ Zb,
      ushort* __restrict__ kvw) {
  const int bh = blockIdx.x;                     // 32
  const int c0 = blockIdx.y * 128;               // 4 c-chunks
  const int b = bh >> 3, h = bh & 7;
  const int t = threadIdx.x;
  __shared__ float kvs[64][64];
  for (int i = t; i < 4096; i += 256)
    kvs[i >> 6][i & 63] = kvm[(size_t)bh * 4096 + i];
  __syncthreads();
  const float zs = (float)cN / Zb[bh];
  const int cl = t & 127, half = t >> 7;         // c-local, d-half
  const int c = c0 + cl;
  float acc[32] = {};
  for (int ec = 0; ec < 64; ec += 8) {
    float w[8];
    #pragma unroll
    for (int e = 0; e < 8; ++e)
      w[e] = Wproj[(size_t)c * cHD + h * 64 + ec + e];
    #pragma unroll
    for (int d = 0; d < 32; ++d)
      #pragma unroll
      for (int e = 0; e < 8; ++e)
        acc[d] = fmaf(kvs[half * 32 + d][ec + e], w[e], acc[d]);
  }
  ushort* dst = kvw + (size_t)b * cC * cHD + (size_t)c * cC + h * 64 + half * 32;
  #pragma unroll
  for (int d = 0; d < 32; ++d) dst[d] = rne_bf16(acc[d] * zs);
}

// ---------------- K6c: A' = RNE_bf16( q · si · sa ), [M][512] token-major; bf16 q in ----------------
__global__ __launch_bounds__(256) void k6c_scaleq(const ushort* __restrict__ q,
      const float* __restrict__ si, const float* __restrict__ Sk,
      ushort* __restrict__ xq) {
  const int bh = blockIdx.x;
  const int b = bh >> 3, head = bh & 7;
  const int n0 = blockIdx.y * 256;
  const int t = threadIdx.x;
  const int wave = t >> 6, lane = t & 63;
  const int g = lane >> 4, j = lane & 15;
  const ushort* qb = q + (size_t)bh * cN * cD;
  const float4 sk4 = *(const float4*)&Sk[bh * 64 + j * 4];
  const float SkE[4] = {sk4.x + kEPS, sk4.y + kEPS, sk4.z + kEPS, sk4.w + kEPS};
  for (int i = 0; i < 16; ++i) {
    const int n = n0 + wave * 64 + i * 4 + g;
    const ushort4 qu = *(const ushort4*)&qb[(size_t)n * cD + j * 4];
    const float q0 = b2f(qu.x), q1 = b2f(qu.y), q2 = b2f(qu.z), q3 = b2f(qu.w);
    float t2 = 0.f;
    t2 = fmaf(q0 + kEPS, SkE[0], t2);
    t2 = fmaf(q1 + kEPS, SkE[1], t2);
    t2 = fmaf(q2 + kEPS, SkE[2], t2);
    t2 = fmaf(q3 + kEPS, SkE[3], t2);
    #pragma unroll
    for (int off = 1; off < 16; off <<= 1) t2 += __shfl_xor(t2, off);
    const float sa_n = 1.f / (1.f + __expf(-(t2 + kEPS)));
    const float s = si[(size_t)bh * cN + n] * sa_n;
    ushort4 hh;
    hh.x = rne_bf16(q0 * s);
    hh.y = rne_bf16(q1 * s);
    hh.z = rne_bf16(q2 * s);
    hh.w = rne_bf16(q3 * s);
    const size_t m = (size_t)b * cN + n;
    *(ushort4*)&xq[m * cC + head * 64 + j * 4] = hh;
  }
}

extern "C" void kernel_launch(void* const* d_in, const int* in_sizes, int n_in,
                              void* d_out, int out_size, void* d_ws, size_t ws_size,
                              hipStream_t stream) {
  (void)in_sizes; (void)n_in; (void)out_size;
  const float* x     = (const float*)d_in[0];
  const float* Wqkv  = (const float*)d_in[1];
  const float* Wproj = (const float*)d_in[2];
  const float* bproj = (const float*)d_in[3];
  float* out = (float*)d_out;
  float* ws  = (float*)d_ws;

  const size_t SLAB = (size_t)cBH * cN * cD;       // 16,777,216 elements
  const size_t OFF_Q   = 0;                        // q bf16 in [0 .. SLAB/2) floats
  const size_t OFF_K   = SLAB;                     // k bf16
  const size_t OFF_V   = 2 * SLAB;                 // v bf16 [first half]; xq [second half]
  const size_t OFF_ACC = 3 * SLAB;
  const size_t ACC_FLOATS = 2048 * 4 + 32 + (size_t)cBH * cD * cD;  // 139,296
  const size_t OFF_R   = OFF_ACC + ACC_FLOATS;     // time-shared region
  const size_t R_FLOATS = (size_t)3 * cHD * cC;    // 786,432 floats (r8-proven fit)
  const size_t TOTAL   = OFF_R + R_FLOATS;
  if (ws_size < TOTAL * sizeof(float)) return;

  ushort* q16 = (ushort*)(ws + OFF_Q);             // SLAB ushorts = 32 MB
  ushort* k16 = (ushort*)(ws + OFF_K);
  ushort* v16 = (ushort*)(ws + OFF_V);
  ushort* xq  = (ushort*)(ws + OFF_V + SLAB / 2);  // disjoint second half of v region
  float* ksum = ws + OFF_ACC;
  float* qsum = ksum + 2048;
  float* Sk   = ksum + 4096;
  float* Sq   = ksum + 6144;
  float* Zb   = ksum + 8192;
  float* kvm  = ksum + 8224;

  // region R timeline (786,432 floats):
  //   [0 .. 393216)         wq bf16 (786,432 ushorts)    alive: round_w -> gemm0
  //   [0 .. 262144)         si                            alive: k34 -> k6c (after gemm0)
  //   [262144 .. 786432)    kvw bf16 (1,048,576 ushorts)  alive: kvw_build -> gemm1
  ushort* wq  = (ushort*)(ws + OFF_R);
  float*  si  = ws + OFF_R;
  ushort* kvw = (ushort*)(ws + OFF_R + (size_t)cBH * cN);   // +262144 floats

  // d_out scratch timeline (gemm1 writes ALL of d_out last, reads none of it):
  //   xs bf16 [0 .. 8M floats)       alive: round_w(x) -> gemm0
  //   kvpart  [8M .. 12M floats)     alive: k45 -> k5r
  //   zpart   [12M .. 12M+1K)        alive: k45 -> k5r
  ushort* xs    = (ushort*)out;                          // 16M ushorts = 32 MB
  float* kvpart = out + (size_t)8 * 1024 * 1024;
  float* zpart  = kvpart + (size_t)KV_SPLIT * cBH * 4096;

  hipMemsetAsync(ksum, 0, ACC_FLOATS * sizeof(float), stream);

  round_w<<<(3 * cHD * cC / 4 + 255) / 256, 256, 0, stream>>>(Wqkv, wq, 3 * cHD * cC / 4);
  round_w<<<((size_t)cM * cC / 4 + 255) / 256, 256, 0, stream>>>(x, xs, cM * cC / 4);
  gemm_mfma<0, 12><<<dim3(cM / 128, (3 * cHD) / 128), 256, 0, stream>>>(
      xs, wq, 0, nullptr, q16, k16, v16, qsum, ksum);
  k34_flow<<<dim3(cBH, cN / 256), 256, 0, stream>>>(q16, k16, qsum, ksum, si, Sq, Sk);
  k45_kv<<<dim3(cBH, KV_SPLIT), 256, 0, stream>>>(k16, v16, Sq, kvpart, zpart);
  k5r_reduce<<<dim3(cBH, 4), 256, 0, stream>>>(kvpart, zpart, kvm, Zb);
  kvw_build<<<dim3(cBH, 4), 256, 0, stream>>>(kvm, Wproj, Zb, kvw);
  k6c_scaleq<<<dim3(cBH, cN / 256), 256, 0, stream>>>(q16, si, Sk, xq);
  gemm_mfma<1, 4><<<dim3(cM / 128, cHD / 128), 256, 0, stream>>>(
      xq, kvw, cC * cHD, bproj, out, nullptr, nullptr, nullptr, nullptr);
}

// Round 13
// 230.547 us; speedup vs baseline: 2.6321x; 1.0515x over previous
//
#include <hip/hip_runtime.h>
#include <hip/hip_bf16.h>

typedef __attribute__((ext_vector_type(8))) short short8;
typedef __attribute__((ext_vector_type(4))) float f32x4;

constexpr int cB = 4, cN = 8192, cC = 512, cH = 8, cD = 64;
constexpr int cM = cB * cN;        // 32768 tokens
constexpr int cHD = cH * cD;       // 512
constexpr int cBH = cB * cH;       // 32
constexpr float kEPS = 1e-6f;
constexpr int KV_SPLIT = 32;       // k45 split-K slices

// ---- RNE f32 -> bf16 (unbiased) ----
__device__ __forceinline__ ushort rne_bf16(float f) {
  unsigned u = __float_as_uint(f);
  u += 0x7fffu + ((u >> 16) & 1u);
  return (ushort)(u >> 16);
}
__device__ __forceinline__ float b2f(ushort u) {
  return __uint_as_float((unsigned)u << 16);
}

// ---------------- rounder: f32 -> single bf16 (RNE); used for Wqkv and x ----------------
__global__ __launch_bounds__(256) void round_w(const float* __restrict__ src,
    ushort* __restrict__ w, int n4) {
  int i = blockIdx.x * 256 + threadIdx.x;
  if (i >= n4) return;
  float4 v = reinterpret_cast<const float4*>(src)[i];
  ushort4 h;
  h.x = rne_bf16(v.x); h.y = rne_bf16(v.y);
  h.z = rne_bf16(v.z); h.w = rne_bf16(v.w);
  reinterpret_cast<ushort4*>(w)[i] = h;
}

// ---------------- single-bf16 MFMA GEMM: C = A[Mx512] @ W[NCx512]^T ----------------
// BK=64: 8 K-steps, per step {8 glds-calls/wave + 16 ds_read_b128 + 32 MFMA},
// 2 barriers/step (halved vs BK=32), single-buffer 32 KB LDS.
// Swizzle (paper-verified): stage linear dest = call-base + lane*16B; source
// unit u^=(row&7); read unit (hh*4+lg)^(r&7) -> 2-way banks (free).
// Bijective XCD-chunked block swizzle (r8-verified).
// EPI=0: epilogue scatters qkv as RNE-bf16 + fused qsum/ksum (f32 pre-round sums).
// EPI=1: epilogue out = acc + bias (f32). bstride = per-b B offset (kvW).
// NOTE (r7 lesson): gemm1 (the d_out writer) reads NOTHING from d_out.
template<int EPI, int NY>
__global__ __launch_bounds__(256) void gemm_mfma(
    const ushort* __restrict__ Ab, const ushort* __restrict__ Wb, int bstride,
    const float* __restrict__ bias,
    void* __restrict__ o0v, void* __restrict__ o1v, void* __restrict__ o2v,
    float* __restrict__ qsum, float* __restrict__ ksum) {
  constexpr int NT = cC / 64;                   // 8 K-steps of BK=64
  __shared__ ushort AhS[128 * 64];              // 16 KB
  __shared__ ushort BhS[128 * 64];              // 16 KB
  __shared__ float colsum[128];
  const int t = threadIdx.x;
  const int wave = t >> 6, lane = t & 63;
  const int wm = wave >> 1, wn = wave & 1;      // 2x2 waves of 64x64
  const int l15 = lane & 15, lg = lane >> 4;

  // ---- XCD-chunked bijective swizzle (nwg % 8 == 0 for both launches) ----
  const int raw = blockIdx.y * gridDim.x + blockIdx.x;
  const int q8 = (int)(gridDim.x * NY) >> 3;
  const int wg2 = (raw & 7) * q8 + (raw >> 3);
  const int rowchunk = wg2 / NY, ycol = wg2 - rowchunk * NY;
  const int row0 = rowchunk * 128, col0 = ycol * 128;
  const size_t wofs = (size_t)(row0 >> 13) * (size_t)bstride;  // per-b B offset

  if (EPI == 0 && t < 128) colsum[t] = 0.f;     // ordered by loop barriers

  f32x4 acc[4][4] = {};

  const int lrow = lane >> 3, lunit = lane & 7; // stage: 8 lanes/row x 16B

#define STAGE_T(basep, base0, dst, k0)                                          \
  _Pragma("unroll")                                                             \
  for (int cc = 0; cc < 4; ++cc) {                                              \
    const int row = wave * 32 + cc * 8 + lrow;                                  \
    const int sw = lunit ^ (row & 7);                                           \
    const size_t goff = (size_t)(base0 + row) * cC + (k0) + sw * 8;             \
    __builtin_amdgcn_global_load_lds(                                           \
        (const __attribute__((address_space(1))) void*)(basep + goff),          \
        (__attribute__((address_space(3))) void*)(&dst[(wave * 32 + cc * 8) * 64]), \
        16, 0, 0);                                                              \
  }

  for (int kt = 0; kt < NT; ++kt) {
    STAGE_T(Ab, row0, AhS, kt * 64);
    STAGE_T((Wb + wofs), col0, BhS, kt * 64);
    __syncthreads();
    short8 ah[4][2];
    #pragma unroll
    for (int mi = 0; mi < 4; ++mi) {
      const int r = wm * 64 + mi * 16 + l15;
      #pragma unroll
      for (int hh = 0; hh < 2; ++hh)
        ah[mi][hh] = *reinterpret_cast<const short8*>(
            &AhS[r * 64 + ((hh * 4 + lg) ^ (r & 7)) * 8]);
    }
    #pragma unroll
    for (int ni = 0; ni < 4; ++ni) {
      const int c = wn * 64 + ni * 16 + l15;
      const short8 bh0 = *reinterpret_cast<const short8*>(
          &BhS[c * 64 + ((lg) ^ (c & 7)) * 8]);
      const short8 bh1 = *reinterpret_cast<const short8*>(
          &BhS[c * 64 + ((4 + lg) ^ (c & 7)) * 8]);
      #pragma unroll
      for (int mi = 0; mi < 4; ++mi) {
        acc[mi][ni] = __builtin_amdgcn_mfma_f32_16x16x32_bf16(ah[mi][0], bh0, acc[mi][ni], 0, 0, 0);
        acc[mi][ni] = __builtin_amdgcn_mfma_f32_16x16x32_bf16(ah[mi][1], bh1, acc[mi][ni], 0, 0, 0);
      }
    }
    __syncthreads();
  }
#undef STAGE_T

  // ---- epilogue: C/D map col=lane&15, row=(lane>>4)*4+r ----
  const bool qk_block = (EPI == 0) && (ycol < 8);
  float csum[4] = {};
  #pragma unroll
  for (int mi = 0; mi < 4; ++mi) {
    #pragma unroll
    for (int ni = 0; ni < 4; ++ni) {
      const int col = col0 + wn * 64 + ni * 16 + l15;
      #pragma unroll
      for (int r = 0; r < 4; ++r) {
        const int m = row0 + wm * 64 + mi * 16 + lg * 4 + r;
        const float val = acc[mi][ni][r];
        if (EPI == 0) {
          const int which = col >> 9;
          const int c2 = col & 511;
          const int h = c2 >> 6, d = c2 & 63;
          const int bb = m >> 13, n = m & 8191;
          const size_t idx = (((size_t)(bb * cH + h)) * cN + n) * cD + d;
          if (which < 2) {
            const float sv = 1.f / (1.f + __expf(-val));
            if (which == 0) ((ushort*)o0v)[idx] = rne_bf16(sv);
            else            ((ushort*)o1v)[idx] = rne_bf16(sv);
            csum[ni] += sv;
          } else {
            ((ushort*)o2v)[idx] = rne_bf16(val * 0.125f);
          }
        } else {
          ((float*)o0v)[(size_t)m * cC + col] = val + bias[col];
        }
      }
    }
  }
  if (qk_block) {
    #pragma unroll
    for (int ni = 0; ni < 4; ++ni)
      atomicAdd(&colsum[wn * 64 + ni * 16 + l15], csum[ni]);
    __syncthreads();
    if (t < 128) {
      const int col = col0 + t;
      const int c2 = col & 511;
      const int h = c2 >> 6, d = c2 & 63;
      const int bb = row0 >> 13;
      float* tgt = (col < 512) ? qsum : ksum;
      atomicAdd(&tgt[(bb * cH + h) * cD + d], colsum[t]);
    }
  }
}

// ---------------- K34: si, so; accumulate Sq, Sk (bf16 q/k inputs) ----------------
__global__ __launch_bounds__(256) void k34_flow(const ushort* __restrict__ q,
      const ushort* __restrict__ k, const float* __restrict__ qsum,
      const float* __restrict__ ksum, float* __restrict__ si,
      float* __restrict__ Sq, float* __restrict__ Sk) {
  const int bh = blockIdx.x;
  const int n0 = blockIdx.y * 256;
  const int t = threadIdx.x;
  const int wave = t >> 6, lane = t & 63;
  const int g = lane >> 4, j = lane & 15;
  const ushort* qb = q + (size_t)bh * cN * cD;
  const ushort* kb = k + (size_t)bh * cN * cD;
  const float4 ks4 = *(const float4*)&ksum[bh * 64 + j * 4];
  const float4 qs4 = *(const float4*)&qsum[bh * 64 + j * 4];
  const float ksd[4] = {ks4.x + kEPS, ks4.y + kEPS, ks4.z + kEPS, ks4.w + kEPS};
  const float qsd[4] = {qs4.x + kEPS, qs4.y + kEPS, qs4.z + kEPS, qs4.w + kEPS};
  float aSq[4] = {}, aSk[4] = {};
  for (int i = 0; i < 16; ++i) {
    const int n = n0 + wave * 64 + i * 4 + g;
    const ushort4 qu = *(const ushort4*)&qb[(size_t)n * cD + j * 4];
    const ushort4 ku = *(const ushort4*)&kb[(size_t)n * cD + j * 4];
    const float qa[4] = {b2f(qu.x), b2f(qu.y), b2f(qu.z), b2f(qu.w)};
    const float ka[4] = {b2f(ku.x), b2f(ku.y), b2f(ku.z), b2f(ku.w)};
    float t1 = 0.f, t2 = 0.f;
    #pragma unroll
    for (int c = 0; c < 4; ++c) {
      t1 = fmaf(qa[c] + kEPS, ksd[c], t1);
      t2 = fmaf(ka[c] + kEPS, qsd[c], t2);
    }
    #pragma unroll
    for (int off = 1; off < 16; off <<= 1) {
      t1 += __shfl_xor(t1, off);
      t2 += __shfl_xor(t2, off);
    }
    const float si_n = 1.f / (t1 + kEPS);
    const float so_n = 1.f / (t2 + kEPS);
    if (j == 0) si[(size_t)bh * cN + n] = si_n;
    #pragma unroll
    for (int c = 0; c < 4; ++c) {
      aSq[c] = fmaf(qa[c], si_n, aSq[c]);
      aSk[c] = fmaf(ka[c], so_n, aSk[c]);
    }
  }
  #pragma unroll
  for (int c = 0; c < 4; ++c) {
    aSq[c] += __shfl_xor(aSq[c], 16); aSq[c] += __shfl_xor(aSq[c], 32);
    aSk[c] += __shfl_xor(aSk[c], 16); aSk[c] += __shfl_xor(aSk[c], 32);
  }
  __shared__ float sAq[4][64], sAk[4][64];
  if (g == 0) {
    #pragma unroll
    for (int c = 0; c < 4; ++c) { sAq[wave][j * 4 + c] = aSq[c]; sAk[wave][j * 4 + c] = aSk[c]; }
  }
  __syncthreads();
  if (t < 64) {
    atomicAdd(&Sq[bh * 64 + t], sAq[0][t] + sAq[1][t] + sAq[2][t] + sAq[3][t]);
    atomicAdd(&Sk[bh * 64 + t], sAk[0][t] + sAk[1][t] + sAk[2][t] + sAk[3][t]);
  }
}

// ---------------- K45: split-K kv partials (NO atomics), ev inline; bf16 k/v in ----------------
__global__ __launch_bounds__(256) void k45_kv(const ushort* __restrict__ kk_,
      const ushort* __restrict__ vv, const float* __restrict__ Sq,
      float* __restrict__ kvpart, float* __restrict__ zpart) {
  const int bh = blockIdx.x;
  const int y = blockIdx.y;                       // KV_SPLIT slices
  constexpr int ROWS = cN / KV_SPLIT;             // 256
  const int n0 = y * ROWS;
  const int t = threadIdx.x;
  const int d = t & 63, eb = t >> 6;
  const int g = t >> 4, j = t & 15;               // 16 ev-groups of 16 lanes
  const int sr = t >> 4, sc = (t & 15) * 4;       // stage mapping
  const ushort* kb = kk_ + (size_t)bh * cN * cD;
  const ushort* vb = vv + (size_t)bh * cN * cD;
  const float4 sq4 = *(const float4*)&Sq[bh * 64 + j * 4];
  const float SqE[4] = {sq4.x + kEPS, sq4.y + kEPS, sq4.z + kEPS, sq4.w + kEPS};
  __shared__ float ks[32][64];
  __shared__ float vs[32][64];
  __shared__ float evs[32];
  __shared__ float zl[16];
  float acc[16] = {};
  float zacc = 0.f;
  ushort4 pk0 = *(const ushort4*)&kb[(size_t)(n0 + sr) * cD + sc];
  ushort4 pk1 = *(const ushort4*)&kb[(size_t)(n0 + 16 + sr) * cD + sc];
  ushort4 pv0 = *(const ushort4*)&vb[(size_t)(n0 + sr) * cD + sc];
  ushort4 pv1 = *(const ushort4*)&vb[(size_t)(n0 + 16 + sr) * cD + sc];
  for (int c0 = 0; c0 < ROWS; c0 += 32) {
    __syncthreads();
    *(float4*)&ks[sr][sc]      = make_float4(b2f(pk0.x), b2f(pk0.y), b2f(pk0.z), b2f(pk0.w));
    *(float4*)&ks[sr + 16][sc] = make_float4(b2f(pk1.x), b2f(pk1.y), b2f(pk1.z), b2f(pk1.w));
    *(float4*)&vs[sr][sc]      = make_float4(b2f(pv0.x), b2f(pv0.y), b2f(pv0.z), b2f(pv0.w));
    *(float4*)&vs[sr + 16][sc] = make_float4(b2f(pv1.x), b2f(pv1.y), b2f(pv1.z), b2f(pv1.w));
    __syncthreads();
    if (c0 + 32 < ROWS) {
      pk0 = *(const ushort4*)&kb[(size_t)(n0 + c0 + 32 + sr) * cD + sc];
      pk1 = *(const ushort4*)&kb[(size_t)(n0 + c0 + 48 + sr) * cD + sc];
      pv0 = *(const ushort4*)&vb[(size_t)(n0 + c0 + 32 + sr) * cD + sc];
      pv1 = *(const ushort4*)&vb[(size_t)(n0 + c0 + 48 + sr) * cD + sc];
    }
    #pragma unroll
    for (int rr = 0; rr < 2; ++rr) {
      const int r = g * 2 + rr;
      const float4 kk4 = *(const float4*)&ks[r][j * 4];
      float tt = 0.f;
      tt = fmaf(kk4.x + kEPS, SqE[0], tt);
      tt = fmaf(kk4.y + kEPS, SqE[1], tt);
      tt = fmaf(kk4.z + kEPS, SqE[2], tt);
      tt = fmaf(kk4.w + kEPS, SqE[3], tt);
      #pragma unroll
      for (int off = 1; off < 16; off <<= 1) tt += __shfl_xor(tt, off);
      if (j == 0) {
        const float cs = fminf(fmaxf(tt + kEPS, -1.f), 1.f);
        const float e = __expf(cs);
        evs[r] = e;
        zacc += e;
      }
    }
    __syncthreads();
    #pragma unroll
    for (int r = 0; r < 32; ++r) {
      const float kd = ks[r][d] * evs[r];
      #pragma unroll
      for (int j2 = 0; j2 < 16; ++j2)
        acc[j2] = fmaf(kd, vs[r][eb * 16 + j2], acc[j2]);
    }
  }
  if (j == 0) zl[g] = zacc;
  __syncthreads();
  if (t == 0) {
    float z = 0.f;
    #pragma unroll
    for (int i = 0; i < 16; ++i) z += zl[i];
    zpart[y * cBH + bh] = z;
  }
  float* kvb = kvpart + ((size_t)y * cBH + bh) * 4096 + d * 64 + eb * 16;
  #pragma unroll
  for (int j2 = 0; j2 < 16; ++j2) kvb[j2] = acc[j2];
}

// ---------------- K5R: fold split-K partials -> kvm, Zb (deterministic) ----------------
__global__ __launch_bounds__(256) void k5r_reduce(const float* __restrict__ kvpart,
      const float* __restrict__ zpart, float* __restrict__ kvm, float* __restrict__ Zb) {
  const int bh = blockIdx.x;
  const int yq = blockIdx.y;                      // 4 chunks of 1024
  const int t = threadIdx.x;
  for (int i = yq * 1024 + t; i < (yq + 1) * 1024; i += 256) {
    float s = 0.f;
    #pragma unroll
    for (int yy = 0; yy < KV_SPLIT; ++yy)
      s += kvpart[((size_t)yy * cBH + bh) * 4096 + i];
    kvm[(size_t)bh * 4096 + i] = s;
  }
  if (yq == 0 && t == 0) {
    float z = 0.f;
    #pragma unroll
    for (int yy = 0; yy < KV_SPLIT; ++yy) z += zpart[yy * cBH + bh];
    Zb[bh] = z;
  }
}

// ---------------- KVW: kvw[b][c*512 + h*64+d] = RNE( (N/Z)·(kv_bh @ Wproj_h^T)[d,c] ) ----------------
__global__ __launch_bounds__(256) void kvw_build(const float* __restrict__ kvm,
      const float* __restrict__ Wproj, const float* __restrict__ Zb,
      ushort* __restrict__ kvw) {
  const int bh = blockIdx.x;                     // 32
  const int c0 = blockIdx.y * 128;               // 4 c-chunks
  const int b = bh >> 3, h = bh & 7;
  const int t = threadIdx.x;
  __shared__ float kvs[64][64];
  for (int i = t; i < 4096; i += 256)
    kvs[i >> 6][i & 63] = kvm[(size_t)bh * 4096 + i];
  __syncthreads();
  const float zs = (float)cN / Zb[bh];
  const int cl = t & 127, half = t >> 7;         // c-local, d-half
  const int c = c0 + cl;
  float acc[32] = {};
  for (int ec = 0; ec < 64; ec += 8) {
    float w[8];
    #pragma unroll
    for (int e = 0; e < 8; ++e)
      w[e] = Wproj[(size_t)c * cHD + h * 64 + ec + e];
    #pragma unroll
    for (int d = 0; d < 32; ++d)
      #pragma unroll
      for (int e = 0; e < 8; ++e)
        acc[d] = fmaf(kvs[half * 32 + d][ec + e], w[e], acc[d]);
  }
  ushort* dst = kvw + (size_t)b * cC * cHD + (size_t)c * cC + h * 64 + half * 32;
  #pragma unroll
  for (int d = 0; d < 32; ++d) dst[d] = rne_bf16(acc[d] * zs);
}

// ---------------- K6c: A' = RNE_bf16( q · si · sa ), [M][512] token-major; bf16 q in ----------------
__global__ __launch_bounds__(256) void k6c_scaleq(const ushort* __restrict__ q,
      const float* __restrict__ si, const float* __restrict__ Sk,
      ushort* __restrict__ xq) {
  const int bh = blockIdx.x;
  const int b = bh >> 3, head = bh & 7;
  const int n0 = blockIdx.y * 256;
  const int t = threadIdx.x;
  const int wave = t >> 6, lane = t & 63;
  const int g = lane >> 4, j = lane & 15;
  const ushort* qb = q + (size_t)bh * cN * cD;
  const float4 sk4 = *(const float4*)&Sk[bh * 64 + j * 4];
  const float SkE[4] = {sk4.x + kEPS, sk4.y + kEPS, sk4.z + kEPS, sk4.w + kEPS};
  for (int i = 0; i < 16; ++i) {
    const int n = n0 + wave * 64 + i * 4 + g;
    const ushort4 qu = *(const ushort4*)&qb[(size_t)n * cD + j * 4];
    const float q0 = b2f(qu.x), q1 = b2f(qu.y), q2 = b2f(qu.z), q3 = b2f(qu.w);
    float t2 = 0.f;
    t2 = fmaf(q0 + kEPS, SkE[0], t2);
    t2 = fmaf(q1 + kEPS, SkE[1], t2);
    t2 = fmaf(q2 + kEPS, SkE[2], t2);
    t2 = fmaf(q3 + kEPS, SkE[3], t2);
    #pragma unroll
    for (int off = 1; off < 16; off <<= 1) t2 += __shfl_xor(t2, off);
    const float sa_n = 1.f / (1.f + __expf(-(t2 + kEPS)));
    const float s = si[(size_t)bh * cN + n] * sa_n;
    ushort4 hh;
    hh.x = rne_bf16(q0 * s);
    hh.y = rne_bf16(q1 * s);
    hh.z = rne_bf16(q2 * s);
    hh.w = rne_bf16(q3 * s);
    const size_t m = (size_t)b * cN + n;
    *(ushort4*)&xq[m * cC + head * 64 + j * 4] = hh;
  }
}

extern "C" void kernel_launch(void* const* d_in, const int* in_sizes, int n_in,
                              void* d_out, int out_size, void* d_ws, size_t ws_size,
                              hipStream_t stream) {
  (void)in_sizes; (void)n_in; (void)out_size;
  const float* x     = (const float*)d_in[0];
  const float* Wqkv  = (const float*)d_in[1];
  const float* Wproj = (const float*)d_in[2];
  const float* bproj = (const float*)d_in[3];
  float* out = (float*)d_out;
  float* ws  = (float*)d_ws;

  const size_t SLAB = (size_t)cBH * cN * cD;       // 16,777,216 elements
  const size_t OFF_Q   = 0;                        // q bf16
  const size_t OFF_K   = SLAB;                     // k bf16
  const size_t OFF_V   = 2 * SLAB;                 // v bf16 [first half]; xq [second half]
  const size_t OFF_ACC = 3 * SLAB;
  const size_t ACC_FLOATS = 2048 * 4 + 32 + (size_t)cBH * cD * cD;  // 139,296
  const size_t OFF_R   = OFF_ACC + ACC_FLOATS;     // time-shared region
  const size_t R_FLOATS = (size_t)3 * cHD * cC;    // 786,432 floats (r8-proven fit)
  const size_t TOTAL   = OFF_R + R_FLOATS;
  if (ws_size < TOTAL * sizeof(float)) return;

  ushort* q16 = (ushort*)(ws + OFF_Q);             // SLAB ushorts = 32 MB
  ushort* k16 = (ushort*)(ws + OFF_K);
  ushort* v16 = (ushort*)(ws + OFF_V);
  ushort* xq  = (ushort*)(ws + OFF_V + SLAB / 2);  // disjoint second half of v region
  float* ksum = ws + OFF_ACC;
  float* qsum = ksum + 2048;
  float* Sk   = ksum + 4096;
  float* Sq   = ksum + 6144;
  float* Zb   = ksum + 8192;
  float* kvm  = ksum + 8224;

  // region R timeline (786,432 floats):
  //   [0 .. 393216)         wq bf16 (786,432 ushorts)    alive: round_w -> gemm0
  //   [0 .. 262144)         si                            alive: k34 -> k6c (after gemm0)
  //   [262144 .. 786432)    kvw bf16 (1,048,576 ushorts)  alive: kvw_build -> gemm1
  ushort* wq  = (ushort*)(ws + OFF_R);
  float*  si  = ws + OFF_R;
  ushort* kvw = (ushort*)(ws + OFF_R + (size_t)cBH * cN);   // +262144 floats

  // d_out scratch timeline (gemm1 writes ALL of d_out last, reads none of it):
  //   xs bf16 [0 .. 8M floats)       alive: round_w(x) -> gemm0
  //   kvpart  [8M .. 12M floats)     alive: k45 -> k5r
  //   zpart   [12M .. 12M+1K)        alive: k45 -> k5r
  ushort* xs    = (ushort*)out;                          // 16M ushorts = 32 MB
  float* kvpart = out + (size_t)8 * 1024 * 1024;
  float* zpart  = kvpart + (size_t)KV_SPLIT * cBH * 4096;

  hipMemsetAsync(ksum, 0, ACC_FLOATS * sizeof(float), stream);

  round_w<<<(3 * cHD * cC / 4 + 255) / 256, 256, 0, stream>>>(Wqkv, wq, 3 * cHD * cC / 4);
  round_w<<<((size_t)cM * cC / 4 + 255) / 256, 256, 0, stream>>>(x, xs, cM * cC / 4);
  gemm_mfma<0, 12><<<dim3(cM / 128, (3 * cHD) / 128), 256, 0, stream>>>(
      xs, wq, 0, nullptr, q16, k16, v16, qsum, ksum);
  k34_flow<<<dim3(cBH, cN / 256), 256, 0, stream>>>(q16, k16, qsum, ksum, si, Sq, Sk);
  k45_kv<<<dim3(cBH, KV_SPLIT), 256, 0, stream>>>(k16, v16, Sq, kvpart, zpart);
  k5r_reduce<<<dim3(cBH, 4), 256, 0, stream>>>(kvpart, zpart, kvm, Zb);
  kvw_build<<<dim3(cBH, 4), 256, 0, stream>>>(kvm, Wproj, Zb, kvw);
  k6c_scaleq<<<dim3(cBH, cN / 256), 256, 0, stream>>>(q16, si, Sk, xq);
  gemm_mfma<1, 4><<<dim3(cM / 128, cHD / 128), 256, 0, stream>>>(
      xq, kvw, cC * cHD, bproj, out, nullptr, nullptr, nullptr, nullptr);
}